// Round 1
// baseline (2211.506 us; speedup 1.0000x reference)
//
#include <hip/hip_runtime.h>

#define IN_F 128
#define HID_F 64
#define OUT_F 8

// ---------------------------------------------------------------------------
// k1: per-node projection. y1 = x @ W1_l ; r1 = x @ W1_r + b1
// thread t -> node = t>>6, h = t&63. Wave (64 lanes) covers one node's 64 hid
// outputs: x[n][k] load broadcasts across the wave, W rows are coalesced.
// ---------------------------------------------------------------------------
__global__ __launch_bounds__(256) void k1_proj(
    const float* __restrict__ x,
    const float* __restrict__ Wl,
    const float* __restrict__ Wr,
    const float* __restrict__ b1,
    float* __restrict__ y1,
    float* __restrict__ r1,
    int n_nodes) {
  int t = blockIdx.x * blockDim.x + threadIdx.x;
  int node = t >> 6;
  int h = t & 63;
  if (node >= n_nodes) return;
  const float* xr = x + (size_t)node * IN_F;
  float accL = 0.f, accR = 0.f;
#pragma unroll 8
  for (int k = 0; k < IN_F; ++k) {
    float xv = xr[k];
    accL += xv * Wl[k * HID_F + h];
    accR += xv * Wr[k * HID_F + h];
  }
  size_t o = (size_t)node * HID_F + h;
  y1[o] = accL;
  r1[o] = accR + b1[h];
}

// ---------------------------------------------------------------------------
// k2: layer-1 edge scatter. agg1[dst] += y1[src] (64 f32), deg[dst] += 1.
// 16 threads per edge, each reads one float4 of the src row and does 4
// native fp32 atomics into the dst row.
// ---------------------------------------------------------------------------
__global__ __launch_bounds__(256) void k2_scatter1(
    const int* __restrict__ src,
    const int* __restrict__ dst,
    const float* __restrict__ y1,
    float* __restrict__ agg1,
    float* __restrict__ deg,
    int n_edges) {
  long long t = (long long)blockIdx.x * blockDim.x + threadIdx.x;
  int e = (int)(t >> 4);
  int lane = (int)(t & 15);
  if (e >= n_edges) return;
  int s = src[e];
  int d = dst[e];
  float4 v = ((const float4*)(y1 + (size_t)s * HID_F))[lane];
  float* out = agg1 + (size_t)d * HID_F + lane * 4;
  unsafeAtomicAdd(out + 0, v.x);
  unsafeAtomicAdd(out + 1, v.y);
  unsafeAtomicAdd(out + 2, v.z);
  unsafeAtomicAdd(out + 3, v.w);
  if (lane == 0) unsafeAtomicAdd(deg + d, 1.0f);
}

// ---------------------------------------------------------------------------
// k3: h = relu(agg1/max(deg,1) + r1) * (mask > 0.5) * 2   (writes over y1 buf)
// ---------------------------------------------------------------------------
__global__ __launch_bounds__(256) void k3_hidden(
    const float* __restrict__ agg1,
    const float* __restrict__ r1,
    const float* __restrict__ deg,
    const float* __restrict__ mask,
    float* __restrict__ hbuf,
    int n_nodes) {
  int t = blockIdx.x * blockDim.x + threadIdx.x;
  int node = t >> 6;
  if (node >= n_nodes) return;
  size_t o = (size_t)t;
  float dv = fmaxf(deg[node], 1.0f);
  float v = agg1[o] / dv + r1[o];
  v = fmaxf(v, 0.0f);
  v = (mask[o] > 0.5f) ? v * 2.0f : 0.0f;
  hbuf[o] = v;
}

// ---------------------------------------------------------------------------
// k3b: z = h @ W2_l  ([N,8]); thread per (node, out)
// ---------------------------------------------------------------------------
__global__ __launch_bounds__(256) void k3b_z(
    const float* __restrict__ h,
    const float* __restrict__ W2l,
    float* __restrict__ z,
    int n_nodes) {
  int t = blockIdx.x * blockDim.x + threadIdx.x;
  int node = t >> 3;
  int o = t & 7;
  if (node >= n_nodes) return;
  const float* hr = h + (size_t)node * HID_F;
  float acc = 0.f;
#pragma unroll 8
  for (int k = 0; k < HID_F; ++k) acc += hr[k] * W2l[k * OUT_F + o];
  z[(size_t)node * OUT_F + o] = acc;
}

// ---------------------------------------------------------------------------
// k4: layer-2 edge scatter. agg2[dst] += z[src] (8 f32). 2 threads/edge.
// ---------------------------------------------------------------------------
__global__ __launch_bounds__(256) void k4_scatter2(
    const int* __restrict__ src,
    const int* __restrict__ dst,
    const float* __restrict__ z,
    float* __restrict__ agg2,
    int n_edges) {
  long long t = (long long)blockIdx.x * blockDim.x + threadIdx.x;
  int e = (int)(t >> 1);
  int lane = (int)(t & 1);
  if (e >= n_edges) return;
  int s = src[e];
  int d = dst[e];
  float4 v = ((const float4*)(z + (size_t)s * OUT_F))[lane];
  float* out = agg2 + (size_t)d * OUT_F + lane * 4;
  unsafeAtomicAdd(out + 0, v.x);
  unsafeAtomicAdd(out + 1, v.y);
  unsafeAtomicAdd(out + 2, v.z);
  unsafeAtomicAdd(out + 3, v.w);
}

// ---------------------------------------------------------------------------
// k5: out[b] = agg2[i]/max(deg,1) + h[i] @ W2_r + b2,  i = idx[b]
// ---------------------------------------------------------------------------
__global__ __launch_bounds__(256) void k5_out(
    const int* __restrict__ idx,
    const float* __restrict__ agg2,
    const float* __restrict__ deg,
    const float* __restrict__ h,
    const float* __restrict__ W2r,
    const float* __restrict__ b2,
    float* __restrict__ out,
    int n_batch) {
  int t = blockIdx.x * blockDim.x + threadIdx.x;
  int b = t >> 3;
  int o = t & 7;
  if (b >= n_batch) return;
  int i = idx[b];
  float dv = fmaxf(deg[i], 1.0f);
  float acc = agg2[(size_t)i * OUT_F + o] / dv + b2[o];
  const float* hr = h + (size_t)i * HID_F;
#pragma unroll 8
  for (int k = 0; k < HID_F; ++k) acc += hr[k] * W2r[k * OUT_F + o];
  out[(size_t)b * OUT_F + o] = acc;
}

extern "C" void kernel_launch(void* const* d_in, const int* in_sizes, int n_in,
                              void* d_out, int out_size, void* d_ws, size_t ws_size,
                              hipStream_t stream) {
  const float* x    = (const float*)d_in[0];
  const int*   ei   = (const int*)d_in[1];
  const int*   idx  = (const int*)d_in[2];
  const float* mask = (const float*)d_in[3];
  const float* W1l  = (const float*)d_in[4];
  const float* W1r  = (const float*)d_in[5];
  const float* b1   = (const float*)d_in[6];
  const float* W2l  = (const float*)d_in[7];
  const float* W2r  = (const float*)d_in[8];
  const float* b2   = (const float*)d_in[9];
  float* out = (float*)d_out;

  int n_nodes = in_sizes[0] / IN_F;
  int n_edges = in_sizes[1] / 2;
  int n_batch = in_sizes[2];
  const int* src = ei;
  const int* dst = ei + n_edges;

  // workspace layout (floats); y1 buffer is reused for h after k2
  float* ws = (float*)d_ws;
  size_t off = 0;
  float* y1   = ws + off; off += (size_t)n_nodes * HID_F;   // later: h
  float* r1   = ws + off; off += (size_t)n_nodes * HID_F;
  float* agg1 = ws + off; off += (size_t)n_nodes * HID_F;
  float* z    = ws + off; off += (size_t)n_nodes * OUT_F;
  float* agg2 = ws + off; off += (size_t)n_nodes * OUT_F;
  float* deg  = ws + off; off += (size_t)n_nodes;

  // zero accumulators (ws is poisoned 0xAA before every call)
  hipMemsetAsync(agg1, 0, (size_t)n_nodes * HID_F * sizeof(float), stream);
  hipMemsetAsync(agg2, 0, (size_t)n_nodes * OUT_F * sizeof(float), stream);
  hipMemsetAsync(deg,  0, (size_t)n_nodes * sizeof(float), stream);

  {
    long long th = (long long)n_nodes * HID_F;
    k1_proj<<<(int)((th + 255) / 256), 256, 0, stream>>>(x, W1l, W1r, b1, y1, r1, n_nodes);
  }
  {
    long long th = (long long)n_edges * 16;
    k2_scatter1<<<(int)((th + 255) / 256), 256, 0, stream>>>(src, dst, y1, agg1, deg, n_edges);
  }
  float* h = y1;  // reuse
  {
    long long th = (long long)n_nodes * HID_F;
    k3_hidden<<<(int)((th + 255) / 256), 256, 0, stream>>>(agg1, r1, deg, mask, h, n_nodes);
  }
  {
    long long th = (long long)n_nodes * OUT_F;
    k3b_z<<<(int)((th + 255) / 256), 256, 0, stream>>>(h, W2l, z, n_nodes);
  }
  {
    long long th = (long long)n_edges * 2;
    k4_scatter2<<<(int)((th + 255) / 256), 256, 0, stream>>>(src, dst, z, agg2, n_edges);
  }
  {
    long long th = (long long)n_batch * OUT_F;
    k5_out<<<(int)((th + 255) / 256), 256, 0, stream>>>(idx, agg2, deg, h, W2r, b2, out, n_batch);
  }
}

// Round 2
// 920.352 us; speedup vs baseline: 2.4029x; 2.4029x over previous
//
#include <hip/hip_runtime.h>

#define IN_F 128
#define HID_F 64
#define OUT_F 8

// ---------------------------------------------------------------------------
// CSR build step 1: histogram of dst
// ---------------------------------------------------------------------------
__global__ __launch_bounds__(256) void hist_kernel(
    const int* __restrict__ dst, int* __restrict__ deg_i, int n_edges) {
  int e = blockIdx.x * blockDim.x + threadIdx.x;
  if (e >= n_edges) return;
  atomicAdd(&deg_i[dst[e]], 1);
}

// ---------------------------------------------------------------------------
// CSR build step 2: exclusive scan over deg_i (single workgroup, 256 threads)
// writes offs[] and a second copy cursor[] for the scatter pass.
// ---------------------------------------------------------------------------
__global__ __launch_bounds__(256) void scan_kernel(
    const int* __restrict__ deg_i, int* __restrict__ offs,
    int* __restrict__ cursor, int n) {
  __shared__ int sums[256];
  int tid = threadIdx.x;
  int chunk = (n + 255) / 256;
  int start = tid * chunk;
  int end = min(start + chunk, n);
  int s = 0;
  for (int i = start; i < end; ++i) s += deg_i[i];
  sums[tid] = s;
  __syncthreads();
  // Hillis-Steele inclusive scan in LDS
  for (int d = 1; d < 256; d <<= 1) {
    int v = 0;
    if (tid >= d) v = sums[tid - d];
    __syncthreads();
    if (tid >= d) sums[tid] += v;
    __syncthreads();
  }
  int run = (tid == 0) ? 0 : sums[tid - 1];
  for (int i = start; i < end; ++i) {
    offs[i] = run;
    cursor[i] = run;
    run += deg_i[i];
  }
}

// ---------------------------------------------------------------------------
// CSR build step 3: scatter edge src ids into csr_src buckets
// ---------------------------------------------------------------------------
__global__ __launch_bounds__(256) void scatter_kernel(
    const int* __restrict__ src, const int* __restrict__ dst,
    int* __restrict__ cursor, int* __restrict__ csr_src, int n_edges) {
  int e = blockIdx.x * blockDim.x + threadIdx.x;
  if (e >= n_edges) return;
  int p = atomicAdd(&cursor[dst[e]], 1);
  csr_src[p] = src[e];
}

// ---------------------------------------------------------------------------
// k1: per-node projection. y1 = x @ W1_l ; r1 = x @ W1_r + b1
// wave covers one node's 64 hidden outputs; x loads broadcast, W coalesced.
// ---------------------------------------------------------------------------
__global__ __launch_bounds__(256) void k1_proj(
    const float* __restrict__ x,
    const float* __restrict__ Wl,
    const float* __restrict__ Wr,
    const float* __restrict__ b1,
    float* __restrict__ y1,
    float* __restrict__ r1,
    int n_nodes) {
  int t = blockIdx.x * blockDim.x + threadIdx.x;
  int node = t >> 6;
  int h = t & 63;
  if (node >= n_nodes) return;
  const float* xr = x + (size_t)node * IN_F;
  float accL = 0.f, accR = 0.f;
#pragma unroll 8
  for (int k = 0; k < IN_F; ++k) {
    float xv = xr[k];
    accL += xv * Wl[k * HID_F + h];
    accR += xv * Wr[k * HID_F + h];
  }
  size_t o = (size_t)node * HID_F + h;
  y1[o] = accL;
  r1[o] = accR + b1[h];
}

// ---------------------------------------------------------------------------
// agg1_fused: one wave per dst node, lane = hidden feature.
// Register-accumulate gathered y1 rows over the node's CSR edge list, then
// fuse: mean -> +r1 -> relu -> dropout -> h.  No atomics, no agg buffer.
// ---------------------------------------------------------------------------
__global__ __launch_bounds__(256) void agg1_fused(
    const float* __restrict__ y1,
    const float* __restrict__ r1,
    const int* __restrict__ deg_i,
    const int* __restrict__ offs,
    const int* __restrict__ csr_src,
    const float* __restrict__ mask,
    float* __restrict__ h,
    int n_nodes) {
  int node = (blockIdx.x * blockDim.x + threadIdx.x) >> 6;
  int lane = threadIdx.x & 63;
  if (node >= n_nodes) return;
  int beg = offs[node];
  int d = deg_i[node];
  float acc = 0.f;
  int j = 0;
  // 4-wide unroll: independent index loads + independent row gathers in flight
  for (; j + 4 <= d; j += 4) {
    int s0 = csr_src[beg + j + 0];
    int s1 = csr_src[beg + j + 1];
    int s2 = csr_src[beg + j + 2];
    int s3 = csr_src[beg + j + 3];
    float v0 = y1[(size_t)s0 * HID_F + lane];
    float v1 = y1[(size_t)s1 * HID_F + lane];
    float v2 = y1[(size_t)s2 * HID_F + lane];
    float v3 = y1[(size_t)s3 * HID_F + lane];
    acc += v0 + v1 + v2 + v3;
  }
  for (; j < d; ++j) {
    int s = csr_src[beg + j];
    acc += y1[(size_t)s * HID_F + lane];
  }
  float dv = fmaxf((float)d, 1.0f);
  size_t o = (size_t)node * HID_F + lane;
  float v = acc / dv + r1[o];
  v = fmaxf(v, 0.0f);
  v = (mask[o] > 0.5f) ? v * 2.0f : 0.0f;
  h[o] = v;
}

// ---------------------------------------------------------------------------
// k3b: z = h @ W2_l  ([N,8]); thread per (node, out)
// ---------------------------------------------------------------------------
__global__ __launch_bounds__(256) void k3b_z(
    const float* __restrict__ h,
    const float* __restrict__ W2l,
    float* __restrict__ z,
    int n_nodes) {
  int t = blockIdx.x * blockDim.x + threadIdx.x;
  int node = t >> 3;
  int o = t & 7;
  if (node >= n_nodes) return;
  const float* hr = h + (size_t)node * HID_F;
  float acc = 0.f;
#pragma unroll 8
  for (int k = 0; k < HID_F; ++k) acc += hr[k] * W2l[k * OUT_F + o];
  z[(size_t)node * OUT_F + o] = acc;
}

// ---------------------------------------------------------------------------
// out_fused: one wave per batch element. Layer-2 aggregation is computed ONLY
// at the 16384 sampled nodes. lane = e8*8 + o: 8 edge-subgroups x 8 features.
// Gathers z rows over CSR edges of idx[b], plus root term h[i] @ W2_r, then
// butterfly-reduce over subgroups.
// ---------------------------------------------------------------------------
__global__ __launch_bounds__(256) void out_fused(
    const int* __restrict__ idx,
    const float* __restrict__ z,
    const int* __restrict__ deg_i,
    const int* __restrict__ offs,
    const int* __restrict__ csr_src,
    const float* __restrict__ h,
    const float* __restrict__ W2r,
    const float* __restrict__ b2,
    float* __restrict__ out,
    int n_batch) {
  int b = (blockIdx.x * blockDim.x + threadIdx.x) >> 6;
  int lane = threadIdx.x & 63;
  if (b >= n_batch) return;
  int i = idx[b];
  int e8 = lane >> 3;   // edge subgroup 0..7
  int o = lane & 7;     // output feature
  int beg = offs[i];
  int d = deg_i[i];
  float acc = 0.f;
  for (int j = e8; j < d; j += 8) {
    int s = csr_src[beg + j];
    acc += z[(size_t)s * OUT_F + o];
  }
  float dv = fmaxf((float)d, 1.0f);
  float v = acc / dv;
  // root term: each subgroup handles 8 contiguous k of the 64-dim dot product
  const float* hr = h + (size_t)i * HID_F;
#pragma unroll
  for (int jj = 0; jj < 8; ++jj) {
    int k = e8 * 8 + jj;
    v += hr[k] * W2r[k * OUT_F + o];
  }
  // reduce across the 8 subgroups (xor on lane bits 3..5)
  v += __shfl_xor(v, 8);
  v += __shfl_xor(v, 16);
  v += __shfl_xor(v, 32);
  if (e8 == 0) out[(size_t)b * OUT_F + o] = v + b2[o];
}

extern "C" void kernel_launch(void* const* d_in, const int* in_sizes, int n_in,
                              void* d_out, int out_size, void* d_ws, size_t ws_size,
                              hipStream_t stream) {
  const float* x    = (const float*)d_in[0];
  const int*   ei   = (const int*)d_in[1];
  const int*   idx  = (const int*)d_in[2];
  const float* mask = (const float*)d_in[3];
  const float* W1l  = (const float*)d_in[4];
  const float* W1r  = (const float*)d_in[5];
  const float* b1   = (const float*)d_in[6];
  const float* W2l  = (const float*)d_in[7];
  const float* W2r  = (const float*)d_in[8];
  const float* b2   = (const float*)d_in[9];
  float* out = (float*)d_out;

  int n_nodes = in_sizes[0] / IN_F;
  int n_edges = in_sizes[1] / 2;
  int n_batch = in_sizes[2];
  const int* src = ei;
  const int* dst = ei + n_edges;

  // workspace layout
  char* ws = (char*)d_ws;
  size_t off = 0;
  float* y1 = (float*)(ws + off); off += (size_t)n_nodes * HID_F * 4;
  float* r1 = (float*)(ws + off); off += (size_t)n_nodes * HID_F * 4;
  float* h  = (float*)(ws + off); off += (size_t)n_nodes * HID_F * 4;
  float* z  = (float*)(ws + off); off += (size_t)n_nodes * OUT_F * 4;
  int* deg_i   = (int*)(ws + off); off += (size_t)n_nodes * 4;
  int* offs    = (int*)(ws + off); off += (size_t)n_nodes * 4;
  int* cursor  = (int*)(ws + off); off += (size_t)n_nodes * 4;
  int* csr_src = (int*)(ws + off); off += (size_t)n_edges * 4;

  // zero the histogram (ws is poisoned 0xAA before every call)
  hipMemsetAsync(deg_i, 0, (size_t)n_nodes * sizeof(int), stream);

  // --- CSR build ---
  hist_kernel<<<(n_edges + 255) / 256, 256, 0, stream>>>(dst, deg_i, n_edges);
  scan_kernel<<<1, 256, 0, stream>>>(deg_i, offs, cursor, n_nodes);
  scatter_kernel<<<(n_edges + 255) / 256, 256, 0, stream>>>(src, dst, cursor, csr_src, n_edges);

  // --- layer 1 ---
  {
    long long th = (long long)n_nodes * HID_F;
    k1_proj<<<(int)((th + 255) / 256), 256, 0, stream>>>(x, W1l, W1r, b1, y1, r1, n_nodes);
    agg1_fused<<<(int)((th + 255) / 256), 256, 0, stream>>>(y1, r1, deg_i, offs, csr_src, mask, h, n_nodes);
  }

  // --- layer 2 (aggregation only at idx nodes, fused into output) ---
  {
    long long th = (long long)n_nodes * OUT_F;
    k3b_z<<<(int)((th + 255) / 256), 256, 0, stream>>>(h, W2l, z, n_nodes);
  }
  {
    long long th = (long long)n_batch * 64;
    out_fused<<<(int)((th + 255) / 256), 256, 0, stream>>>(idx, z, deg_i, offs, csr_src, h, W2r, b2, out, n_batch);
  }
}

// Round 3
// 673.129 us; speedup vs baseline: 3.2854x; 1.3673x over previous
//
#include <hip/hip_runtime.h>

#define IN_F 128
#define HID_F 64
#define OUT_F 8

// ---------------------------------------------------------------------------
// CSR build step 1: histogram of dst
// ---------------------------------------------------------------------------
__global__ __launch_bounds__(256) void hist_kernel(
    const int* __restrict__ dst, int* __restrict__ deg_i, int n_edges) {
  int e = blockIdx.x * blockDim.x + threadIdx.x;
  if (e >= n_edges) return;
  atomicAdd(&deg_i[dst[e]], 1);
}

// ---------------------------------------------------------------------------
// CSR build step 2: exclusive scan over deg_i (single workgroup, 1024 threads)
// ---------------------------------------------------------------------------
__global__ __launch_bounds__(1024) void scan_kernel(
    const int* __restrict__ deg_i, int* __restrict__ offs,
    int* __restrict__ cursor, int n) {
  __shared__ int sums[1024];
  int tid = threadIdx.x;
  int chunk = (n + 1023) / 1024;
  int start = tid * chunk;
  int end = min(start + chunk, n);
  int s = 0;
  for (int i = start; i < end; ++i) s += deg_i[i];
  sums[tid] = s;
  __syncthreads();
  for (int d = 1; d < 1024; d <<= 1) {
    int v = 0;
    if (tid >= d) v = sums[tid - d];
    __syncthreads();
    if (tid >= d) sums[tid] += v;
    __syncthreads();
  }
  int run = (tid == 0) ? 0 : sums[tid - 1];
  for (int i = start; i < end; ++i) {
    offs[i] = run;
    cursor[i] = run;
    run += deg_i[i];
  }
}

// ---------------------------------------------------------------------------
// CSR build step 3: scatter edge src ids into csr_src buckets
// ---------------------------------------------------------------------------
__global__ __launch_bounds__(256) void scatter_kernel(
    const int* __restrict__ src, const int* __restrict__ dst,
    int* __restrict__ cursor, int* __restrict__ csr_src, int n_edges) {
  int e = blockIdx.x * blockDim.x + threadIdx.x;
  if (e >= n_edges) return;
  int p = atomicAdd(&cursor[dst[e]], 1);
  csr_src[p] = src[e];
}

// ---------------------------------------------------------------------------
// k1: LDS-tiled GEMM. [n x 128] @ [128 x 128] where cols = [W1_l | W1_r].
// Block: 256 threads = 16 tx (8-output groups) x 16 ty (8-node groups).
// Tile: 128 nodes. K blocked by 32. XS transposed [k][node], WS [k][out].
// Each thread: 8x8 register micro-tile -> per k: 4 ds_read_b128 + 64 FMA.
// ---------------------------------------------------------------------------
#define BM 128
#define BK 32
__global__ __launch_bounds__(256, 4) void k1_proj(
    const float* __restrict__ x,
    const float* __restrict__ Wl,
    const float* __restrict__ Wr,
    const float* __restrict__ b1,
    float* __restrict__ y1,
    float* __restrict__ r1,
    int n_nodes) {
  __shared__ float XS[BK][BM];     // 16 KB
  __shared__ float WS[BK][128];    // 16 KB
  int tid = threadIdx.x;
  int tx = tid & 15;      // out group: outs tx*8 .. tx*8+7 (of 128 concat)
  int ty = tid >> 4;      // node group: nodes ty*8 .. ty*8+7
  int n0 = blockIdx.x * BM;

  float acc[8][8];
#pragma unroll
  for (int i = 0; i < 8; ++i)
#pragma unroll
    for (int j = 0; j < 8; ++j) acc[i][j] = 0.f;

  for (int kb = 0; kb < IN_F; kb += BK) {
    // stage XS (transposed): 128 nodes x 32 k
    {
      int node = tid >> 3;          // 0..31
      int k4 = (tid & 7) * 4;
#pragma unroll
      for (int p = 0; p < 4; ++p) {
        int nn = node + p * 32;
        int gs = min(n0 + nn, n_nodes - 1);
        float4 v = *(const float4*)(x + (size_t)gs * IN_F + kb + k4);
        XS[k4 + 0][nn] = v.x;
        XS[k4 + 1][nn] = v.y;
        XS[k4 + 2][nn] = v.z;
        XS[k4 + 3][nn] = v.w;
      }
    }
    // stage WS: 32 k x 128 outs (L | R)
    {
#pragma unroll
      for (int p = 0; p < 4; ++p) {
        int s = tid + p * 256;      // float4 slot, 1024 total
        int k = s >> 5;
        int col = (s & 31) * 4;
        const float* sp = (col < 64) ? (Wl + (size_t)(kb + k) * HID_F + col)
                                     : (Wr + (size_t)(kb + k) * HID_F + (col - 64));
        *(float4*)&WS[k][col] = *(const float4*)sp;
      }
    }
    __syncthreads();
#pragma unroll 4
    for (int k = 0; k < BK; ++k) {
      float4 xa = *(const float4*)&XS[k][ty * 8];
      float4 xb = *(const float4*)&XS[k][ty * 8 + 4];
      float4 wa = *(const float4*)&WS[k][tx * 8];
      float4 wb = *(const float4*)&WS[k][tx * 8 + 4];
      float xs[8] = {xa.x, xa.y, xa.z, xa.w, xb.x, xb.y, xb.z, xb.w};
      float ws[8] = {wa.x, wa.y, wa.z, wa.w, wb.x, wb.y, wb.z, wb.w};
#pragma unroll
      for (int i = 0; i < 8; ++i)
#pragma unroll
        for (int j = 0; j < 8; ++j) acc[i][j] += xs[i] * ws[j];
    }
    __syncthreads();
  }

  // epilogue: outs < 64 -> y1 ; outs >= 64 -> r1 (+ b1)
  int outb = tx * 8;
  bool isR = (outb >= HID_F);
  int ob = isR ? outb - HID_F : outb;
  float bb[8];
#pragma unroll
  for (int j = 0; j < 8; ++j) bb[j] = isR ? b1[ob + j] : 0.f;
  float* dbuf = isR ? r1 : y1;
#pragma unroll
  for (int i = 0; i < 8; ++i) {
    int node = n0 + ty * 8 + i;
    if (node < n_nodes) {
      float4 o0 = make_float4(acc[i][0] + bb[0], acc[i][1] + bb[1],
                              acc[i][2] + bb[2], acc[i][3] + bb[3]);
      float4 o1 = make_float4(acc[i][4] + bb[4], acc[i][5] + bb[5],
                              acc[i][6] + bb[6], acc[i][7] + bb[7]);
      *(float4*)(dbuf + (size_t)node * HID_F + ob) = o0;
      *(float4*)(dbuf + (size_t)node * HID_F + ob + 4) = o1;
    }
  }
}

// ---------------------------------------------------------------------------
// agg1_fused: one wave per dst node, lane = hidden feature.
// mean(y1[neighbors]) -> +r1 -> relu -> dropout -> h. No atomics.
// ---------------------------------------------------------------------------
__global__ __launch_bounds__(256) void agg1_fused(
    const float* __restrict__ y1,
    const float* __restrict__ r1,
    const int* __restrict__ deg_i,
    const int* __restrict__ offs,
    const int* __restrict__ csr_src,
    const float* __restrict__ mask,
    float* __restrict__ h,
    int n_nodes) {
  int node = (blockIdx.x * blockDim.x + threadIdx.x) >> 6;
  int lane = threadIdx.x & 63;
  if (node >= n_nodes) return;
  int beg = offs[node];
  int d = deg_i[node];
  float acc = 0.f;
  int j = 0;
  for (; j + 4 <= d; j += 4) {
    int s0 = csr_src[beg + j + 0];
    int s1 = csr_src[beg + j + 1];
    int s2 = csr_src[beg + j + 2];
    int s3 = csr_src[beg + j + 3];
    float v0 = y1[(size_t)s0 * HID_F + lane];
    float v1 = y1[(size_t)s1 * HID_F + lane];
    float v2 = y1[(size_t)s2 * HID_F + lane];
    float v3 = y1[(size_t)s3 * HID_F + lane];
    acc += v0 + v1 + v2 + v3;
  }
  for (; j < d; ++j) {
    int s = csr_src[beg + j];
    acc += y1[(size_t)s * HID_F + lane];
  }
  float dv = fmaxf((float)d, 1.0f);
  size_t o = (size_t)node * HID_F + lane;
  float v = acc / dv + r1[o];
  v = fmaxf(v, 0.0f);
  v = (mask[o] > 0.5f) ? v * 2.0f : 0.0f;
  h[o] = v;
}

// ---------------------------------------------------------------------------
// k3b: z = h @ W2_l ([N,8]). One node per thread, 8 register accumulators,
// float4 h loads, W2_l staged in LDS (broadcast reads).
// ---------------------------------------------------------------------------
__global__ __launch_bounds__(256) void k3b_z(
    const float* __restrict__ h,
    const float* __restrict__ W2l,
    float* __restrict__ z,
    int n_nodes) {
  __shared__ float WS[HID_F][OUT_F];   // 2 KB
  int tid = threadIdx.x;
  if (tid < 128) {
    float4 w = *(const float4*)(W2l + tid * 4);
    *(float4*)&WS[tid >> 1][(tid & 1) * 4] = w;
  }
  __syncthreads();
  int node = blockIdx.x * blockDim.x + tid;
  if (node >= n_nodes) return;
  const float* hr = h + (size_t)node * HID_F;
  float acc[8] = {0, 0, 0, 0, 0, 0, 0, 0};
  for (int k = 0; k < HID_F; k += 4) {
    float4 hv = *(const float4*)(hr + k);
    float hh[4] = {hv.x, hv.y, hv.z, hv.w};
#pragma unroll
    for (int j = 0; j < 4; ++j) {
      float4 w0 = *(const float4*)&WS[k + j][0];
      float4 w1 = *(const float4*)&WS[k + j][4];
      acc[0] += hh[j] * w0.x; acc[1] += hh[j] * w0.y;
      acc[2] += hh[j] * w0.z; acc[3] += hh[j] * w0.w;
      acc[4] += hh[j] * w1.x; acc[5] += hh[j] * w1.y;
      acc[6] += hh[j] * w1.z; acc[7] += hh[j] * w1.w;
    }
  }
  float* zp = z + (size_t)node * OUT_F;
  *(float4*)(zp + 0) = make_float4(acc[0], acc[1], acc[2], acc[3]);
  *(float4*)(zp + 4) = make_float4(acc[4], acc[5], acc[6], acc[7]);
}

// ---------------------------------------------------------------------------
// out_fused: one wave per batch element; layer-2 aggregation only at idx nodes.
// lane = e8*8 + o: 8 edge-subgroups x 8 features; butterfly-reduce subgroups.
// ---------------------------------------------------------------------------
__global__ __launch_bounds__(256) void out_fused(
    const int* __restrict__ idx,
    const float* __restrict__ z,
    const int* __restrict__ deg_i,
    const int* __restrict__ offs,
    const int* __restrict__ csr_src,
    const float* __restrict__ h,
    const float* __restrict__ W2r,
    const float* __restrict__ b2,
    float* __restrict__ out,
    int n_batch) {
  int b = (blockIdx.x * blockDim.x + threadIdx.x) >> 6;
  int lane = threadIdx.x & 63;
  if (b >= n_batch) return;
  int i = idx[b];
  int e8 = lane >> 3;
  int o = lane & 7;
  int beg = offs[i];
  int d = deg_i[i];
  float acc = 0.f;
  for (int j = e8; j < d; j += 8) {
    int s = csr_src[beg + j];
    acc += z[(size_t)s * OUT_F + o];
  }
  float dv = fmaxf((float)d, 1.0f);
  float v = acc / dv;
  const float* hr = h + (size_t)i * HID_F;
#pragma unroll
  for (int jj = 0; jj < 8; ++jj) {
    int k = e8 * 8 + jj;
    v += hr[k] * W2r[k * OUT_F + o];
  }
  v += __shfl_xor(v, 8);
  v += __shfl_xor(v, 16);
  v += __shfl_xor(v, 32);
  if (e8 == 0) out[(size_t)b * OUT_F + o] = v + b2[o];
}

extern "C" void kernel_launch(void* const* d_in, const int* in_sizes, int n_in,
                              void* d_out, int out_size, void* d_ws, size_t ws_size,
                              hipStream_t stream) {
  const float* x    = (const float*)d_in[0];
  const int*   ei   = (const int*)d_in[1];
  const int*   idx  = (const int*)d_in[2];
  const float* mask = (const float*)d_in[3];
  const float* W1l  = (const float*)d_in[4];
  const float* W1r  = (const float*)d_in[5];
  const float* b1   = (const float*)d_in[6];
  const float* W2l  = (const float*)d_in[7];
  const float* W2r  = (const float*)d_in[8];
  const float* b2   = (const float*)d_in[9];
  float* out = (float*)d_out;

  int n_nodes = in_sizes[0] / IN_F;
  int n_edges = in_sizes[1] / 2;
  int n_batch = in_sizes[2];
  const int* src = ei;
  const int* dst = ei + n_edges;

  // workspace layout
  char* ws = (char*)d_ws;
  size_t off = 0;
  float* y1 = (float*)(ws + off); off += (size_t)n_nodes * HID_F * 4;
  float* r1 = (float*)(ws + off); off += (size_t)n_nodes * HID_F * 4;
  float* h  = (float*)(ws + off); off += (size_t)n_nodes * HID_F * 4;
  float* z  = (float*)(ws + off); off += (size_t)n_nodes * OUT_F * 4;
  int* deg_i   = (int*)(ws + off); off += (size_t)n_nodes * 4;
  int* offs    = (int*)(ws + off); off += (size_t)n_nodes * 4;
  int* cursor  = (int*)(ws + off); off += (size_t)n_nodes * 4;
  int* csr_src = (int*)(ws + off); off += (size_t)n_edges * 4;

  hipMemsetAsync(deg_i, 0, (size_t)n_nodes * sizeof(int), stream);

  // --- CSR build ---
  hist_kernel<<<(n_edges + 255) / 256, 256, 0, stream>>>(dst, deg_i, n_edges);
  scan_kernel<<<1, 1024, 0, stream>>>(deg_i, offs, cursor, n_nodes);
  scatter_kernel<<<(n_edges + 255) / 256, 256, 0, stream>>>(src, dst, cursor, csr_src, n_edges);

  // --- layer 1 ---
  k1_proj<<<(n_nodes + BM - 1) / BM, 256, 0, stream>>>(x, W1l, W1r, b1, y1, r1, n_nodes);
  {
    long long th = (long long)n_nodes * HID_F;
    agg1_fused<<<(int)((th + 255) / 256), 256, 0, stream>>>(y1, r1, deg_i, offs, csr_src, mask, h, n_nodes);
  }

  // --- layer 2 ---
  k3b_z<<<(n_nodes + 255) / 256, 256, 0, stream>>>(h, W2l, z, n_nodes);
  {
    long long th = (long long)n_batch * 64;
    out_fused<<<(int)((th + 255) / 256), 256, 0, stream>>>(idx, z, deg_i, offs, csr_src, h, W2r, b2, out, n_batch);
  }
}

// Round 4
// 453.203 us; speedup vs baseline: 4.8797x; 1.4853x over previous
//
#include <hip/hip_runtime.h>

#define IN_F 128
#define HID_F 64
#define OUT_F 8

// ---------------------------------------------------------------------------
// CSR build step 1: histogram of dst
// ---------------------------------------------------------------------------
__global__ __launch_bounds__(256) void hist_kernel(
    const int* __restrict__ dst, int* __restrict__ deg_i, int n_edges) {
  int e = blockIdx.x * blockDim.x + threadIdx.x;
  if (e >= n_edges) return;
  atomicAdd(&deg_i[dst[e]], 1);
}

// ---------------------------------------------------------------------------
// CSR build step 2: device-wide exclusive scan, 3 phases.
// Phase A: per-block (1024 elems) local exclusive prefix + block total.
// ---------------------------------------------------------------------------
__global__ __launch_bounds__(256) void scan_local(
    const int* __restrict__ deg_i, int* __restrict__ offs,
    int* __restrict__ blk_sums, int n) {
  __shared__ int tsum[256];
  int t = threadIdx.x;
  int i0 = blockIdx.x * 1024 + t * 4;
  int v0 = 0, v1 = 0, v2 = 0, v3 = 0;
  if (i0 + 3 < n) {
    int4 d = *(const int4*)(deg_i + i0);
    v0 = d.x; v1 = d.y; v2 = d.z; v3 = d.w;
  } else {
    if (i0 + 0 < n) v0 = deg_i[i0 + 0];
    if (i0 + 1 < n) v1 = deg_i[i0 + 1];
    if (i0 + 2 < n) v2 = deg_i[i0 + 2];
    if (i0 + 3 < n) v3 = deg_i[i0 + 3];
  }
  tsum[t] = v0 + v1 + v2 + v3;
  __syncthreads();
  for (int d = 1; d < 256; d <<= 1) {
    int x = 0;
    if (t >= d) x = tsum[t - d];
    __syncthreads();
    if (t >= d) tsum[t] += x;
    __syncthreads();
  }
  if (t == 255) blk_sums[blockIdx.x] = tsum[255];
  int run = (t == 0) ? 0 : tsum[t - 1];
  int o0 = run, o1 = o0 + v0, o2 = o1 + v1, o3 = o2 + v2;
  if (i0 + 3 < n) {
    *(int4*)(offs + i0) = make_int4(o0, o1, o2, o3);
  } else {
    if (i0 + 0 < n) offs[i0 + 0] = o0;
    if (i0 + 1 < n) offs[i0 + 1] = o1;
    if (i0 + 2 < n) offs[i0 + 2] = o2;
    if (i0 + 3 < n) offs[i0 + 3] = o3;
  }
}

// Phase B: exclusive scan of block totals (nblk <= 256) in a single block.
__global__ __launch_bounds__(256) void scan_blk(
    int* __restrict__ blk_sums, int nblk) {
  __shared__ int s[256];
  int t = threadIdx.x;
  s[t] = (t < nblk) ? blk_sums[t] : 0;
  __syncthreads();
  for (int d = 1; d < 256; d <<= 1) {
    int x = 0;
    if (t >= d) x = s[t - d];
    __syncthreads();
    if (t >= d) s[t] += x;
    __syncthreads();
  }
  if (t < nblk) blk_sums[t] = (t == 0) ? 0 : s[t - 1];
}

// Phase C: add block base; write final offs and cursor copy.
__global__ __launch_bounds__(256) void scan_add(
    int* __restrict__ offs, int* __restrict__ cursor,
    const int* __restrict__ blk_sums, int n) {
  int base = blk_sums[blockIdx.x];
  int i0 = blockIdx.x * 1024 + threadIdx.x * 4;
  if (i0 + 3 < n) {
    int4 o = *(const int4*)(offs + i0);
    o.x += base; o.y += base; o.z += base; o.w += base;
    *(int4*)(offs + i0) = o;
    *(int4*)(cursor + i0) = o;
  } else {
    for (int j = 0; j < 4; ++j)
      if (i0 + j < n) {
        int v = offs[i0 + j] + base;
        offs[i0 + j] = v;
        cursor[i0 + j] = v;
      }
  }
}

// ---------------------------------------------------------------------------
// CSR build step 3: scatter edge src ids into csr_src buckets
// ---------------------------------------------------------------------------
__global__ __launch_bounds__(256) void scatter_kernel(
    const int* __restrict__ src, const int* __restrict__ dst,
    int* __restrict__ cursor, int* __restrict__ csr_src, int n_edges) {
  int e = blockIdx.x * blockDim.x + threadIdx.x;
  if (e >= n_edges) return;
  int p = atomicAdd(&cursor[dst[e]], 1);
  csr_src[p] = src[e];
}

// ---------------------------------------------------------------------------
// k1: LDS-tiled GEMM. [n x 128] @ [128 x 128] where cols = [W1_l | W1_r].
// ---------------------------------------------------------------------------
#define BM 128
#define BK 32
__global__ __launch_bounds__(256, 4) void k1_proj(
    const float* __restrict__ x,
    const float* __restrict__ Wl,
    const float* __restrict__ Wr,
    const float* __restrict__ b1,
    float* __restrict__ y1,
    float* __restrict__ r1,
    int n_nodes) {
  __shared__ float XS[BK][BM];     // 16 KB
  __shared__ float WS[BK][128];    // 16 KB
  int tid = threadIdx.x;
  int tx = tid & 15;
  int ty = tid >> 4;
  int n0 = blockIdx.x * BM;

  float acc[8][8];
#pragma unroll
  for (int i = 0; i < 8; ++i)
#pragma unroll
    for (int j = 0; j < 8; ++j) acc[i][j] = 0.f;

  for (int kb = 0; kb < IN_F; kb += BK) {
    {
      int node = tid >> 3;
      int k4 = (tid & 7) * 4;
#pragma unroll
      for (int p = 0; p < 4; ++p) {
        int nn = node + p * 32;
        int gs = min(n0 + nn, n_nodes - 1);
        float4 v = *(const float4*)(x + (size_t)gs * IN_F + kb + k4);
        XS[k4 + 0][nn] = v.x;
        XS[k4 + 1][nn] = v.y;
        XS[k4 + 2][nn] = v.z;
        XS[k4 + 3][nn] = v.w;
      }
    }
    {
#pragma unroll
      for (int p = 0; p < 4; ++p) {
        int s = tid + p * 256;
        int k = s >> 5;
        int col = (s & 31) * 4;
        const float* sp = (col < 64) ? (Wl + (size_t)(kb + k) * HID_F + col)
                                     : (Wr + (size_t)(kb + k) * HID_F + (col - 64));
        *(float4*)&WS[k][col] = *(const float4*)sp;
      }
    }
    __syncthreads();
#pragma unroll 4
    for (int k = 0; k < BK; ++k) {
      float4 xa = *(const float4*)&XS[k][ty * 8];
      float4 xb = *(const float4*)&XS[k][ty * 8 + 4];
      float4 wa = *(const float4*)&WS[k][tx * 8];
      float4 wb = *(const float4*)&WS[k][tx * 8 + 4];
      float xs[8] = {xa.x, xa.y, xa.z, xa.w, xb.x, xb.y, xb.z, xb.w};
      float ws[8] = {wa.x, wa.y, wa.z, wa.w, wb.x, wb.y, wb.z, wb.w};
#pragma unroll
      for (int i = 0; i < 8; ++i)
#pragma unroll
        for (int j = 0; j < 8; ++j) acc[i][j] += xs[i] * ws[j];
    }
    __syncthreads();
  }

  int outb = tx * 8;
  bool isR = (outb >= HID_F);
  int ob = isR ? outb - HID_F : outb;
  float bb[8];
#pragma unroll
  for (int j = 0; j < 8; ++j) bb[j] = isR ? b1[ob + j] : 0.f;
  float* dbuf = isR ? r1 : y1;
#pragma unroll
  for (int i = 0; i < 8; ++i) {
    int node = n0 + ty * 8 + i;
    if (node < n_nodes) {
      float4 o0 = make_float4(acc[i][0] + bb[0], acc[i][1] + bb[1],
                              acc[i][2] + bb[2], acc[i][3] + bb[3]);
      float4 o1 = make_float4(acc[i][4] + bb[4], acc[i][5] + bb[5],
                              acc[i][6] + bb[6], acc[i][7] + bb[7]);
      *(float4*)(dbuf + (size_t)node * HID_F + ob) = o0;
      *(float4*)(dbuf + (size_t)node * HID_F + ob + 4) = o1;
    }
  }
}

// ---------------------------------------------------------------------------
// agg1_fused: one wave per dst node, lane = hidden feature.
// ---------------------------------------------------------------------------
__global__ __launch_bounds__(256) void agg1_fused(
    const float* __restrict__ y1,
    const float* __restrict__ r1,
    const int* __restrict__ deg_i,
    const int* __restrict__ offs,
    const int* __restrict__ csr_src,
    const float* __restrict__ mask,
    float* __restrict__ h,
    int n_nodes) {
  int node = (blockIdx.x * blockDim.x + threadIdx.x) >> 6;
  int lane = threadIdx.x & 63;
  if (node >= n_nodes) return;
  int beg = offs[node];
  int d = deg_i[node];
  float acc = 0.f;
  int j = 0;
  for (; j + 4 <= d; j += 4) {
    int s0 = csr_src[beg + j + 0];
    int s1 = csr_src[beg + j + 1];
    int s2 = csr_src[beg + j + 2];
    int s3 = csr_src[beg + j + 3];
    float v0 = y1[(size_t)s0 * HID_F + lane];
    float v1 = y1[(size_t)s1 * HID_F + lane];
    float v2 = y1[(size_t)s2 * HID_F + lane];
    float v3 = y1[(size_t)s3 * HID_F + lane];
    acc += v0 + v1 + v2 + v3;
  }
  for (; j < d; ++j) {
    int s = csr_src[beg + j];
    acc += y1[(size_t)s * HID_F + lane];
  }
  float dv = fmaxf((float)d, 1.0f);
  size_t o = (size_t)node * HID_F + lane;
  float v = acc / dv + r1[o];
  v = fmaxf(v, 0.0f);
  v = (mask[o] > 0.5f) ? v * 2.0f : 0.0f;
  h[o] = v;
}

// ---------------------------------------------------------------------------
// k3b: z = h @ W2_l ([N,8]). One node per thread.
// ---------------------------------------------------------------------------
__global__ __launch_bounds__(256) void k3b_z(
    const float* __restrict__ h,
    const float* __restrict__ W2l,
    float* __restrict__ z,
    int n_nodes) {
  __shared__ float WS[HID_F][OUT_F];
  int tid = threadIdx.x;
  if (tid < 128) {
    float4 w = *(const float4*)(W2l + tid * 4);
    *(float4*)&WS[tid >> 1][(tid & 1) * 4] = w;
  }
  __syncthreads();
  int node = blockIdx.x * blockDim.x + tid;
  if (node >= n_nodes) return;
  const float* hr = h + (size_t)node * HID_F;
  float acc[8] = {0, 0, 0, 0, 0, 0, 0, 0};
  for (int k = 0; k < HID_F; k += 4) {
    float4 hv = *(const float4*)(hr + k);
    float hh[4] = {hv.x, hv.y, hv.z, hv.w};
#pragma unroll
    for (int j = 0; j < 4; ++j) {
      float4 w0 = *(const float4*)&WS[k + j][0];
      float4 w1 = *(const float4*)&WS[k + j][4];
      acc[0] += hh[j] * w0.x; acc[1] += hh[j] * w0.y;
      acc[2] += hh[j] * w0.z; acc[3] += hh[j] * w0.w;
      acc[4] += hh[j] * w1.x; acc[5] += hh[j] * w1.y;
      acc[6] += hh[j] * w1.z; acc[7] += hh[j] * w1.w;
    }
  }
  float* zp = z + (size_t)node * OUT_F;
  *(float4*)(zp + 0) = make_float4(acc[0], acc[1], acc[2], acc[3]);
  *(float4*)(zp + 4) = make_float4(acc[4], acc[5], acc[6], acc[7]);
}

// ---------------------------------------------------------------------------
// out_fused: one wave per batch element; layer-2 agg only at idx nodes.
// ---------------------------------------------------------------------------
__global__ __launch_bounds__(256) void out_fused(
    const int* __restrict__ idx,
    const float* __restrict__ z,
    const int* __restrict__ deg_i,
    const int* __restrict__ offs,
    const int* __restrict__ csr_src,
    const float* __restrict__ h,
    const float* __restrict__ W2r,
    const float* __restrict__ b2,
    float* __restrict__ out,
    int n_batch) {
  int b = (blockIdx.x * blockDim.x + threadIdx.x) >> 6;
  int lane = threadIdx.x & 63;
  if (b >= n_batch) return;
  int i = idx[b];
  int e8 = lane >> 3;
  int o = lane & 7;
  int beg = offs[i];
  int d = deg_i[i];
  float acc = 0.f;
  for (int j = e8; j < d; j += 8) {
    int s = csr_src[beg + j];
    acc += z[(size_t)s * OUT_F + o];
  }
  float dv = fmaxf((float)d, 1.0f);
  float v = acc / dv;
  const float* hr = h + (size_t)i * HID_F;
#pragma unroll
  for (int jj = 0; jj < 8; ++jj) {
    int k = e8 * 8 + jj;
    v += hr[k] * W2r[k * OUT_F + o];
  }
  v += __shfl_xor(v, 8);
  v += __shfl_xor(v, 16);
  v += __shfl_xor(v, 32);
  if (e8 == 0) out[(size_t)b * OUT_F + o] = v + b2[o];
}

extern "C" void kernel_launch(void* const* d_in, const int* in_sizes, int n_in,
                              void* d_out, int out_size, void* d_ws, size_t ws_size,
                              hipStream_t stream) {
  const float* x    = (const float*)d_in[0];
  const int*   ei   = (const int*)d_in[1];
  const int*   idx  = (const int*)d_in[2];
  const float* mask = (const float*)d_in[3];
  const float* W1l  = (const float*)d_in[4];
  const float* W1r  = (const float*)d_in[5];
  const float* b1   = (const float*)d_in[6];
  const float* W2l  = (const float*)d_in[7];
  const float* W2r  = (const float*)d_in[8];
  const float* b2   = (const float*)d_in[9];
  float* out = (float*)d_out;

  int n_nodes = in_sizes[0] / IN_F;
  int n_edges = in_sizes[1] / 2;
  int n_batch = in_sizes[2];
  const int* src = ei;
  const int* dst = ei + n_edges;

  // workspace layout
  char* ws = (char*)d_ws;
  size_t off = 0;
  float* y1 = (float*)(ws + off); off += (size_t)n_nodes * HID_F * 4;
  float* r1 = (float*)(ws + off); off += (size_t)n_nodes * HID_F * 4;
  float* h  = (float*)(ws + off); off += (size_t)n_nodes * HID_F * 4;
  float* z  = (float*)(ws + off); off += (size_t)n_nodes * OUT_F * 4;
  int* deg_i   = (int*)(ws + off); off += (size_t)n_nodes * 4;
  int* offs    = (int*)(ws + off); off += (size_t)n_nodes * 4;
  int* cursor  = (int*)(ws + off); off += (size_t)n_nodes * 4;
  int* csr_src = (int*)(ws + off); off += (size_t)n_edges * 4;
  int* blk_sums = (int*)(ws + off); off += 256 * 4;

  hipMemsetAsync(deg_i, 0, (size_t)n_nodes * sizeof(int), stream);

  // --- CSR build ---
  hist_kernel<<<(n_edges + 255) / 256, 256, 0, stream>>>(dst, deg_i, n_edges);
  int nblk = (n_nodes + 1023) / 1024;   // 98 for N=100000 (<=256 required)
  scan_local<<<nblk, 256, 0, stream>>>(deg_i, offs, blk_sums, n_nodes);
  scan_blk<<<1, 256, 0, stream>>>(blk_sums, nblk);
  scan_add<<<nblk, 256, 0, stream>>>(offs, cursor, blk_sums, n_nodes);
  scatter_kernel<<<(n_edges + 255) / 256, 256, 0, stream>>>(src, dst, cursor, csr_src, n_edges);

  // --- layer 1 ---
  k1_proj<<<(n_nodes + BM - 1) / BM, 256, 0, stream>>>(x, W1l, W1r, b1, y1, r1, n_nodes);
  {
    long long th = (long long)n_nodes * HID_F;
    agg1_fused<<<(int)((th + 255) / 256), 256, 0, stream>>>(y1, r1, deg_i, offs, csr_src, mask, h, n_nodes);
  }

  // --- layer 2 ---
  k3b_z<<<(n_nodes + 255) / 256, 256, 0, stream>>>(h, W2l, z, n_nodes);
  {
    long long th = (long long)n_batch * 64;
    out_fused<<<(int)((th + 255) / 256), 256, 0, stream>>>(idx, z, deg_i, offs, csr_src, h, W2r, b2, out, n_batch);
  }
}

// Round 5
// 326.811 us; speedup vs baseline: 6.7669x; 1.3867x over previous
//
#include <hip/hip_runtime.h>

#define IN_F 128
#define HID_F 64
#define OUT_F 8

// Bucketed CSR build: bucket = dst >> 8 (256 nodes per bucket).
// All csr_src lines for a bucket are written by ONE workgroup -> no cross-XCD
// line ping-pong (round-4 profile: 105 MB HBM writes for 6.4 MB of data).
#define BSHIFT 8
#define BGRAN 256
#define CHUNK 4096
#define EPT (CHUNK / 256)   // edges per thread in bucket kernels

// ---------------------------------------------------------------------------
// bucket_count: per-block LDS histogram of dst>>8, one global atomic/bucket.
// ---------------------------------------------------------------------------
__global__ __launch_bounds__(256) void bucket_count(
    const int* __restrict__ dst, int* __restrict__ bucket_cnt, int n_edges) {
  __shared__ int hist[512];
  int t = threadIdx.x;
  for (int i = t; i < 512; i += 256) hist[i] = 0;
  __syncthreads();
  int e0 = blockIdx.x * CHUNK;
#pragma unroll
  for (int k = 0; k < EPT; ++k) {
    int e = e0 + k * 256 + t;
    if (e < n_edges) atomicAdd(&hist[dst[e] >> BSHIFT], 1);
  }
  __syncthreads();
  for (int i = t; i < 512; i += 256) {
    int c = hist[i];
    if (c) atomicAdd(&bucket_cnt[i], c);
  }
}

// ---------------------------------------------------------------------------
// bucket_scan: exclusive scan of bucket counts (nbuk <= 512), one block.
// ---------------------------------------------------------------------------
__global__ __launch_bounds__(512) void bucket_scan(
    const int* __restrict__ cnt, int* __restrict__ boffs,
    int* __restrict__ bcur, int nbuk) {
  __shared__ int s[512];
  int t = threadIdx.x;
  s[t] = (t < nbuk) ? cnt[t] : 0;
  __syncthreads();
  for (int d = 1; d < 512; d <<= 1) {
    int v = 0;
    if (t >= d) v = s[t - d];
    __syncthreads();
    if (t >= d) s[t] += v;
    __syncthreads();
  }
  if (t < nbuk) {
    int e = (t == 0) ? 0 : s[t - 1];
    boffs[t] = e;
    bcur[t] = e;
  }
}

// ---------------------------------------------------------------------------
// bucket_scatter: re-read edge chunk, reserve contiguous per-bucket runs,
// write packed (src,dst) grouped by bucket -> near-full-line writes.
// ---------------------------------------------------------------------------
__global__ __launch_bounds__(256) void bucket_scatter(
    const int* __restrict__ src, const int* __restrict__ dst,
    int* __restrict__ bcur, int2* __restrict__ ebuf, int n_edges) {
  __shared__ int hist[512];
  __shared__ int base[512];
  int t = threadIdx.x;
  for (int i = t; i < 512; i += 256) hist[i] = 0;
  __syncthreads();
  int e0 = blockIdx.x * CHUNK;
  int2 ed[EPT];
  int bk[EPT];
#pragma unroll
  for (int k = 0; k < EPT; ++k) {
    int e = e0 + k * 256 + t;
    if (e < n_edges) {
      ed[k].x = src[e];
      ed[k].y = dst[e];
      bk[k] = ed[k].y >> BSHIFT;
      atomicAdd(&hist[bk[k]], 1);
    } else {
      bk[k] = -1;
    }
  }
  __syncthreads();
  for (int i = t; i < 512; i += 256) {
    int c = hist[i];
    base[i] = c ? atomicAdd(&bcur[i], c) : 0;
  }
  __syncthreads();
  for (int i = t; i < 512; i += 256) hist[i] = 0;
  __syncthreads();
#pragma unroll
  for (int k = 0; k < EPT; ++k) {
    if (bk[k] >= 0) {
      int r = atomicAdd(&hist[bk[k]], 1);
      ebuf[base[bk[k]] + r] = ed[k];
    }
  }
}

// ---------------------------------------------------------------------------
// deg_kernel: one block per bucket; LDS histogram over the bucket's 256
// nodes; coalesced deg_i writes. No global atomics.
// ---------------------------------------------------------------------------
__global__ __launch_bounds__(256) void deg_kernel(
    const int2* __restrict__ ebuf, const int* __restrict__ boffs,
    const int* __restrict__ bcnt, int* __restrict__ deg_i, int n_nodes) {
  __shared__ int hist[BGRAN];
  int b = blockIdx.x;
  int t = threadIdx.x;
  hist[t] = 0;
  __syncthreads();
  int beg = boffs[b];
  int cnt = bcnt[b];
  for (int j = t; j < cnt; j += 256)
    atomicAdd(&hist[ebuf[beg + j].y & (BGRAN - 1)], 1);
  __syncthreads();
  int node = b * BGRAN + t;
  if (node < n_nodes) deg_i[node] = hist[t];
}

// ---------------------------------------------------------------------------
// device-wide exclusive scan over deg_i (3 phases)
// ---------------------------------------------------------------------------
__global__ __launch_bounds__(256) void scan_local(
    const int* __restrict__ deg_i, int* __restrict__ offs,
    int* __restrict__ blk_sums, int n) {
  __shared__ int tsum[256];
  int t = threadIdx.x;
  int i0 = blockIdx.x * 1024 + t * 4;
  int v0 = 0, v1 = 0, v2 = 0, v3 = 0;
  if (i0 + 3 < n) {
    int4 d = *(const int4*)(deg_i + i0);
    v0 = d.x; v1 = d.y; v2 = d.z; v3 = d.w;
  } else {
    if (i0 + 0 < n) v0 = deg_i[i0 + 0];
    if (i0 + 1 < n) v1 = deg_i[i0 + 1];
    if (i0 + 2 < n) v2 = deg_i[i0 + 2];
    if (i0 + 3 < n) v3 = deg_i[i0 + 3];
  }
  tsum[t] = v0 + v1 + v2 + v3;
  __syncthreads();
  for (int d = 1; d < 256; d <<= 1) {
    int x = 0;
    if (t >= d) x = tsum[t - d];
    __syncthreads();
    if (t >= d) tsum[t] += x;
    __syncthreads();
  }
  if (t == 255) blk_sums[blockIdx.x] = tsum[255];
  int run = (t == 0) ? 0 : tsum[t - 1];
  int o0 = run, o1 = o0 + v0, o2 = o1 + v1, o3 = o2 + v2;
  if (i0 + 3 < n) {
    *(int4*)(offs + i0) = make_int4(o0, o1, o2, o3);
  } else {
    if (i0 + 0 < n) offs[i0 + 0] = o0;
    if (i0 + 1 < n) offs[i0 + 1] = o1;
    if (i0 + 2 < n) offs[i0 + 2] = o2;
    if (i0 + 3 < n) offs[i0 + 3] = o3;
  }
}

__global__ __launch_bounds__(256) void scan_blk(
    int* __restrict__ blk_sums, int nblk) {
  __shared__ int s[256];
  int t = threadIdx.x;
  s[t] = (t < nblk) ? blk_sums[t] : 0;
  __syncthreads();
  for (int d = 1; d < 256; d <<= 1) {
    int x = 0;
    if (t >= d) x = s[t - d];
    __syncthreads();
    if (t >= d) s[t] += x;
    __syncthreads();
  }
  if (t < nblk) blk_sums[t] = (t == 0) ? 0 : s[t - 1];
}

__global__ __launch_bounds__(256) void scan_add(
    int* __restrict__ offs, const int* __restrict__ blk_sums, int n) {
  int base = blk_sums[blockIdx.x];
  int i0 = blockIdx.x * 1024 + threadIdx.x * 4;
  if (i0 + 3 < n) {
    int4 o = *(const int4*)(offs + i0);
    o.x += base; o.y += base; o.z += base; o.w += base;
    *(int4*)(offs + i0) = o;
  } else {
    for (int j = 0; j < 4; ++j)
      if (i0 + j < n) offs[i0 + j] += base;
  }
}

// ---------------------------------------------------------------------------
// csr_scatter: one block per bucket; per-node cursors in LDS; csr_src writes
// confined to this bucket's ~16 KB window (single XCD -> lines evicted once).
// ---------------------------------------------------------------------------
__global__ __launch_bounds__(256) void csr_scatter(
    const int2* __restrict__ ebuf, const int* __restrict__ boffs,
    const int* __restrict__ bcnt, const int* __restrict__ offs,
    int* __restrict__ csr_src, int n_nodes) {
  __shared__ int cur[BGRAN];
  int b = blockIdx.x;
  int t = threadIdx.x;
  int node = b * BGRAN + t;
  cur[t] = (node < n_nodes) ? offs[node] : 0;
  __syncthreads();
  int beg = boffs[b];
  int cnt = bcnt[b];
  for (int j = t; j < cnt; j += 256) {
    int2 e = ebuf[beg + j];
    int p = atomicAdd(&cur[e.y & (BGRAN - 1)], 1);
    csr_src[p] = e.x;
  }
}

// ---------------------------------------------------------------------------
// k1: LDS-tiled GEMM. [n x 128] @ [128 x 128] where cols = [W1_l | W1_r].
// ---------------------------------------------------------------------------
#define BM 128
#define BK 32
__global__ __launch_bounds__(256, 4) void k1_proj(
    const float* __restrict__ x,
    const float* __restrict__ Wl,
    const float* __restrict__ Wr,
    const float* __restrict__ b1,
    float* __restrict__ y1,
    float* __restrict__ r1,
    int n_nodes) {
  __shared__ float XS[BK][BM];
  __shared__ float WS[BK][128];
  int tid = threadIdx.x;
  int tx = tid & 15;
  int ty = tid >> 4;
  int n0 = blockIdx.x * BM;

  float acc[8][8];
#pragma unroll
  for (int i = 0; i < 8; ++i)
#pragma unroll
    for (int j = 0; j < 8; ++j) acc[i][j] = 0.f;

  for (int kb = 0; kb < IN_F; kb += BK) {
    {
      int node = tid >> 3;
      int k4 = (tid & 7) * 4;
#pragma unroll
      for (int p = 0; p < 4; ++p) {
        int nn = node + p * 32;
        int gs = min(n0 + nn, n_nodes - 1);
        float4 v = *(const float4*)(x + (size_t)gs * IN_F + kb + k4);
        XS[k4 + 0][nn] = v.x;
        XS[k4 + 1][nn] = v.y;
        XS[k4 + 2][nn] = v.z;
        XS[k4 + 3][nn] = v.w;
      }
    }
    {
#pragma unroll
      for (int p = 0; p < 4; ++p) {
        int s = tid + p * 256;
        int k = s >> 5;
        int col = (s & 31) * 4;
        const float* sp = (col < 64) ? (Wl + (size_t)(kb + k) * HID_F + col)
                                     : (Wr + (size_t)(kb + k) * HID_F + (col - 64));
        *(float4*)&WS[k][col] = *(const float4*)sp;
      }
    }
    __syncthreads();
#pragma unroll 4
    for (int k = 0; k < BK; ++k) {
      float4 xa = *(const float4*)&XS[k][ty * 8];
      float4 xb = *(const float4*)&XS[k][ty * 8 + 4];
      float4 wa = *(const float4*)&WS[k][tx * 8];
      float4 wb = *(const float4*)&WS[k][tx * 8 + 4];
      float xs[8] = {xa.x, xa.y, xa.z, xa.w, xb.x, xb.y, xb.z, xb.w};
      float ws[8] = {wa.x, wa.y, wa.z, wa.w, wb.x, wb.y, wb.z, wb.w};
#pragma unroll
      for (int i = 0; i < 8; ++i)
#pragma unroll
        for (int j = 0; j < 8; ++j) acc[i][j] += xs[i] * ws[j];
    }
    __syncthreads();
  }

  int outb = tx * 8;
  bool isR = (outb >= HID_F);
  int ob = isR ? outb - HID_F : outb;
  float bb[8];
#pragma unroll
  for (int j = 0; j < 8; ++j) bb[j] = isR ? b1[ob + j] : 0.f;
  float* dbuf = isR ? r1 : y1;
#pragma unroll
  for (int i = 0; i < 8; ++i) {
    int node = n0 + ty * 8 + i;
    if (node < n_nodes) {
      float4 o0 = make_float4(acc[i][0] + bb[0], acc[i][1] + bb[1],
                              acc[i][2] + bb[2], acc[i][3] + bb[3]);
      float4 o1 = make_float4(acc[i][4] + bb[4], acc[i][5] + bb[5],
                              acc[i][6] + bb[6], acc[i][7] + bb[7]);
      *(float4*)(dbuf + (size_t)node * HID_F + ob) = o0;
      *(float4*)(dbuf + (size_t)node * HID_F + ob + 4) = o1;
    }
  }
}

// ---------------------------------------------------------------------------
// agg1_fused: one wave per dst node, lane = hidden feature.
// ---------------------------------------------------------------------------
__global__ __launch_bounds__(256) void agg1_fused(
    const float* __restrict__ y1,
    const float* __restrict__ r1,
    const int* __restrict__ deg_i,
    const int* __restrict__ offs,
    const int* __restrict__ csr_src,
    const float* __restrict__ mask,
    float* __restrict__ h,
    int n_nodes) {
  int node = (blockIdx.x * blockDim.x + threadIdx.x) >> 6;
  int lane = threadIdx.x & 63;
  if (node >= n_nodes) return;
  int beg = offs[node];
  int d = deg_i[node];
  float acc = 0.f;
  int j = 0;
  for (; j + 4 <= d; j += 4) {
    int s0 = csr_src[beg + j + 0];
    int s1 = csr_src[beg + j + 1];
    int s2 = csr_src[beg + j + 2];
    int s3 = csr_src[beg + j + 3];
    float v0 = y1[(size_t)s0 * HID_F + lane];
    float v1 = y1[(size_t)s1 * HID_F + lane];
    float v2 = y1[(size_t)s2 * HID_F + lane];
    float v3 = y1[(size_t)s3 * HID_F + lane];
    acc += v0 + v1 + v2 + v3;
  }
  for (; j < d; ++j) {
    int s = csr_src[beg + j];
    acc += y1[(size_t)s * HID_F + lane];
  }
  float dv = fmaxf((float)d, 1.0f);
  size_t o = (size_t)node * HID_F + lane;
  float v = acc / dv + r1[o];
  v = fmaxf(v, 0.0f);
  v = (mask[o] > 0.5f) ? v * 2.0f : 0.0f;
  h[o] = v;
}

// ---------------------------------------------------------------------------
// k3b: z = h @ W2_l ([N,8]). One node per thread.
// ---------------------------------------------------------------------------
__global__ __launch_bounds__(256) void k3b_z(
    const float* __restrict__ h,
    const float* __restrict__ W2l,
    float* __restrict__ z,
    int n_nodes) {
  __shared__ float WS[HID_F][OUT_F];
  int tid = threadIdx.x;
  if (tid < 128) {
    float4 w = *(const float4*)(W2l + tid * 4);
    *(float4*)&WS[tid >> 1][(tid & 1) * 4] = w;
  }
  __syncthreads();
  int node = blockIdx.x * blockDim.x + tid;
  if (node >= n_nodes) return;
  const float* hr = h + (size_t)node * HID_F;
  float acc[8] = {0, 0, 0, 0, 0, 0, 0, 0};
  for (int k = 0; k < HID_F; k += 4) {
    float4 hv = *(const float4*)(hr + k);
    float hh[4] = {hv.x, hv.y, hv.z, hv.w};
#pragma unroll
    for (int j = 0; j < 4; ++j) {
      float4 w0 = *(const float4*)&WS[k + j][0];
      float4 w1 = *(const float4*)&WS[k + j][4];
      acc[0] += hh[j] * w0.x; acc[1] += hh[j] * w0.y;
      acc[2] += hh[j] * w0.z; acc[3] += hh[j] * w0.w;
      acc[4] += hh[j] * w1.x; acc[5] += hh[j] * w1.y;
      acc[6] += hh[j] * w1.z; acc[7] += hh[j] * w1.w;
    }
  }
  float* zp = z + (size_t)node * OUT_F;
  *(float4*)(zp + 0) = make_float4(acc[0], acc[1], acc[2], acc[3]);
  *(float4*)(zp + 4) = make_float4(acc[4], acc[5], acc[6], acc[7]);
}

// ---------------------------------------------------------------------------
// out_fused: one wave per batch element; layer-2 agg only at idx nodes.
// ---------------------------------------------------------------------------
__global__ __launch_bounds__(256) void out_fused(
    const int* __restrict__ idx,
    const float* __restrict__ z,
    const int* __restrict__ deg_i,
    const int* __restrict__ offs,
    const int* __restrict__ csr_src,
    const float* __restrict__ h,
    const float* __restrict__ W2r,
    const float* __restrict__ b2,
    float* __restrict__ out,
    int n_batch) {
  int b = (blockIdx.x * blockDim.x + threadIdx.x) >> 6;
  int lane = threadIdx.x & 63;
  if (b >= n_batch) return;
  int i = idx[b];
  int e8 = lane >> 3;
  int o = lane & 7;
  int beg = offs[i];
  int d = deg_i[i];
  float acc = 0.f;
  for (int j = e8; j < d; j += 8) {
    int s = csr_src[beg + j];
    acc += z[(size_t)s * OUT_F + o];
  }
  float dv = fmaxf((float)d, 1.0f);
  float v = acc / dv;
  const float* hr = h + (size_t)i * HID_F;
#pragma unroll
  for (int jj = 0; jj < 8; ++jj) {
    int k = e8 * 8 + jj;
    v += hr[k] * W2r[k * OUT_F + o];
  }
  v += __shfl_xor(v, 8);
  v += __shfl_xor(v, 16);
  v += __shfl_xor(v, 32);
  if (e8 == 0) out[(size_t)b * OUT_F + o] = v + b2[o];
}

extern "C" void kernel_launch(void* const* d_in, const int* in_sizes, int n_in,
                              void* d_out, int out_size, void* d_ws, size_t ws_size,
                              hipStream_t stream) {
  const float* x    = (const float*)d_in[0];
  const int*   ei   = (const int*)d_in[1];
  const int*   idx  = (const int*)d_in[2];
  const float* mask = (const float*)d_in[3];
  const float* W1l  = (const float*)d_in[4];
  const float* W1r  = (const float*)d_in[5];
  const float* b1   = (const float*)d_in[6];
  const float* W2l  = (const float*)d_in[7];
  const float* W2r  = (const float*)d_in[8];
  const float* b2   = (const float*)d_in[9];
  float* out = (float*)d_out;

  int n_nodes = in_sizes[0] / IN_F;
  int n_edges = in_sizes[1] / 2;
  int n_batch = in_sizes[2];
  const int* src = ei;
  const int* dst = ei + n_edges;

  // workspace layout
  char* ws = (char*)d_ws;
  size_t off = 0;
  float* y1 = (float*)(ws + off); off += (size_t)n_nodes * HID_F * 4;
  float* r1 = (float*)(ws + off); off += (size_t)n_nodes * HID_F * 4;
  float* h  = (float*)(ws + off); off += (size_t)n_nodes * HID_F * 4;
  float* z  = (float*)(ws + off); off += (size_t)n_nodes * OUT_F * 4;
  int* deg_i   = (int*)(ws + off); off += (size_t)n_nodes * 4;
  int* offs    = (int*)(ws + off); off += (size_t)n_nodes * 4;
  int* csr_src = (int*)(ws + off); off += (size_t)n_edges * 4;
  int* blk_sums   = (int*)(ws + off); off += 256 * 4;
  int* bucket_cnt = (int*)(ws + off); off += 512 * 4;
  int* bucket_off = (int*)(ws + off); off += 512 * 4;
  int* bucket_cur = (int*)(ws + off); off += 512 * 4;
  // ebuf (packed edges, 8B each) aliases y1/r1: dead before k1_proj writes them
  int2* ebuf = (int2*)y1;

  int nbuk = (n_nodes + BGRAN - 1) / BGRAN;        // 391 for N=100000 (<=512)
  int nchunk = (n_edges + CHUNK - 1) / CHUNK;      // 391 for E=1.6M

  hipMemsetAsync(bucket_cnt, 0, 512 * sizeof(int), stream);

  // --- bucketed CSR build ---
  bucket_count<<<nchunk, 256, 0, stream>>>(dst, bucket_cnt, n_edges);
  bucket_scan<<<1, 512, 0, stream>>>(bucket_cnt, bucket_off, bucket_cur, nbuk);
  bucket_scatter<<<nchunk, 256, 0, stream>>>(src, dst, bucket_cur, ebuf, n_edges);
  deg_kernel<<<nbuk, 256, 0, stream>>>(ebuf, bucket_off, bucket_cnt, deg_i, n_nodes);
  int nblk = (n_nodes + 1023) / 1024;              // 98 (<=256)
  scan_local<<<nblk, 256, 0, stream>>>(deg_i, offs, blk_sums, n_nodes);
  scan_blk<<<1, 256, 0, stream>>>(blk_sums, nblk);
  scan_add<<<nblk, 256, 0, stream>>>(offs, blk_sums, n_nodes);
  csr_scatter<<<nbuk, 256, 0, stream>>>(ebuf, bucket_off, bucket_cnt, offs, csr_src, n_nodes);

  // --- layer 1 ---
  k1_proj<<<(n_nodes + BM - 1) / BM, 256, 0, stream>>>(x, W1l, W1r, b1, y1, r1, n_nodes);
  {
    long long th = (long long)n_nodes * HID_F;
    agg1_fused<<<(int)((th + 255) / 256), 256, 0, stream>>>(y1, r1, deg_i, offs, csr_src, mask, h, n_nodes);
  }

  // --- layer 2 ---
  k3b_z<<<(n_nodes + 255) / 256, 256, 0, stream>>>(h, W2l, z, n_nodes);
  {
    long long th = (long long)n_batch * 64;
    out_fused<<<(int)((th + 255) / 256), 256, 0, stream>>>(idx, z, deg_i, offs, csr_src, h, W2r, b2, out, n_batch);
  }
}

// Round 6
// 322.348 us; speedup vs baseline: 6.8606x; 1.0138x over previous
//
#include <hip/hip_runtime.h>
#include <hip/hip_fp16.h>

#define IN_F 128
#define HID_F 64
#define OUT_F 8

// Bucketed CSR build: bucket = dst >> 8 (256 nodes per bucket).
#define BSHIFT 8
#define BGRAN 256
#define CHUNK 4096
#define EPT (CHUNK / 256)

// ---------------------------------------------------------------------------
// bucket_count: per-block LDS histogram of dst>>8, one global atomic/bucket.
// ---------------------------------------------------------------------------
__global__ __launch_bounds__(256) void bucket_count(
    const int* __restrict__ dst, int* __restrict__ bucket_cnt, int n_edges) {
  __shared__ int hist[512];
  int t = threadIdx.x;
  for (int i = t; i < 512; i += 256) hist[i] = 0;
  __syncthreads();
  int e0 = blockIdx.x * CHUNK;
#pragma unroll
  for (int k = 0; k < EPT; ++k) {
    int e = e0 + k * 256 + t;
    if (e < n_edges) atomicAdd(&hist[dst[e] >> BSHIFT], 1);
  }
  __syncthreads();
  for (int i = t; i < 512; i += 256) {
    int c = hist[i];
    if (c) atomicAdd(&bucket_cnt[i], c);
  }
}

// ---------------------------------------------------------------------------
// bucket_scan: exclusive scan of bucket counts (nbuk <= 512), one block.
// ---------------------------------------------------------------------------
__global__ __launch_bounds__(512) void bucket_scan(
    const int* __restrict__ cnt, int* __restrict__ boffs,
    int* __restrict__ bcur, int nbuk) {
  __shared__ int s[512];
  int t = threadIdx.x;
  s[t] = (t < nbuk) ? cnt[t] : 0;
  __syncthreads();
  for (int d = 1; d < 512; d <<= 1) {
    int v = 0;
    if (t >= d) v = s[t - d];
    __syncthreads();
    if (t >= d) s[t] += v;
    __syncthreads();
  }
  if (t < nbuk) {
    int e = (t == 0) ? 0 : s[t - 1];
    boffs[t] = e;
    bcur[t] = e;
  }
}

// ---------------------------------------------------------------------------
// bucket_scatter: reserve contiguous per-bucket runs, write packed (src,dst).
// ---------------------------------------------------------------------------
__global__ __launch_bounds__(256) void bucket_scatter(
    const int* __restrict__ src, const int* __restrict__ dst,
    int* __restrict__ bcur, int2* __restrict__ ebuf, int n_edges) {
  __shared__ int hist[512];
  __shared__ int base[512];
  int t = threadIdx.x;
  for (int i = t; i < 512; i += 256) hist[i] = 0;
  __syncthreads();
  int e0 = blockIdx.x * CHUNK;
  int2 ed[EPT];
  int bk[EPT];
#pragma unroll
  for (int k = 0; k < EPT; ++k) {
    int e = e0 + k * 256 + t;
    if (e < n_edges) {
      ed[k].x = src[e];
      ed[k].y = dst[e];
      bk[k] = ed[k].y >> BSHIFT;
      atomicAdd(&hist[bk[k]], 1);
    } else {
      bk[k] = -1;
    }
  }
  __syncthreads();
  for (int i = t; i < 512; i += 256) {
    int c = hist[i];
    base[i] = c ? atomicAdd(&bcur[i], c) : 0;
  }
  __syncthreads();
  for (int i = t; i < 512; i += 256) hist[i] = 0;
  __syncthreads();
#pragma unroll
  for (int k = 0; k < EPT; ++k) {
    if (bk[k] >= 0) {
      int r = atomicAdd(&hist[bk[k]], 1);
      ebuf[base[bk[k]] + r] = ed[k];
    }
  }
}

// ---------------------------------------------------------------------------
// deg_kernel: one block per bucket; LDS histogram; coalesced deg_i writes.
// ---------------------------------------------------------------------------
__global__ __launch_bounds__(256) void deg_kernel(
    const int2* __restrict__ ebuf, const int* __restrict__ boffs,
    const int* __restrict__ bcnt, int* __restrict__ deg_i, int n_nodes) {
  __shared__ int hist[BGRAN];
  int b = blockIdx.x;
  int t = threadIdx.x;
  hist[t] = 0;
  __syncthreads();
  int beg = boffs[b];
  int cnt = bcnt[b];
  for (int j = t; j < cnt; j += 256)
    atomicAdd(&hist[ebuf[beg + j].y & (BGRAN - 1)], 1);
  __syncthreads();
  int node = b * BGRAN + t;
  if (node < n_nodes) deg_i[node] = hist[t];
}

// ---------------------------------------------------------------------------
// device-wide exclusive scan over deg_i (3 phases)
// ---------------------------------------------------------------------------
__global__ __launch_bounds__(256) void scan_local(
    const int* __restrict__ deg_i, int* __restrict__ offs,
    int* __restrict__ blk_sums, int n) {
  __shared__ int tsum[256];
  int t = threadIdx.x;
  int i0 = blockIdx.x * 1024 + t * 4;
  int v0 = 0, v1 = 0, v2 = 0, v3 = 0;
  if (i0 + 3 < n) {
    int4 d = *(const int4*)(deg_i + i0);
    v0 = d.x; v1 = d.y; v2 = d.z; v3 = d.w;
  } else {
    if (i0 + 0 < n) v0 = deg_i[i0 + 0];
    if (i0 + 1 < n) v1 = deg_i[i0 + 1];
    if (i0 + 2 < n) v2 = deg_i[i0 + 2];
    if (i0 + 3 < n) v3 = deg_i[i0 + 3];
  }
  tsum[t] = v0 + v1 + v2 + v3;
  __syncthreads();
  for (int d = 1; d < 256; d <<= 1) {
    int x = 0;
    if (t >= d) x = tsum[t - d];
    __syncthreads();
    if (t >= d) tsum[t] += x;
    __syncthreads();
  }
  if (t == 255) blk_sums[blockIdx.x] = tsum[255];
  int run = (t == 0) ? 0 : tsum[t - 1];
  int o0 = run, o1 = o0 + v0, o2 = o1 + v1, o3 = o2 + v2;
  if (i0 + 3 < n) {
    *(int4*)(offs + i0) = make_int4(o0, o1, o2, o3);
  } else {
    if (i0 + 0 < n) offs[i0 + 0] = o0;
    if (i0 + 1 < n) offs[i0 + 1] = o1;
    if (i0 + 2 < n) offs[i0 + 2] = o2;
    if (i0 + 3 < n) offs[i0 + 3] = o3;
  }
}

__global__ __launch_bounds__(256) void scan_blk(
    int* __restrict__ blk_sums, int nblk) {
  __shared__ int s[256];
  int t = threadIdx.x;
  s[t] = (t < nblk) ? blk_sums[t] : 0;
  __syncthreads();
  for (int d = 1; d < 256; d <<= 1) {
    int x = 0;
    if (t >= d) x = s[t - d];
    __syncthreads();
    if (t >= d) s[t] += x;
    __syncthreads();
  }
  if (t < nblk) blk_sums[t] = (t == 0) ? 0 : s[t - 1];
}

__global__ __launch_bounds__(256) void scan_add(
    int* __restrict__ offs, const int* __restrict__ blk_sums, int n) {
  int base = blk_sums[blockIdx.x];
  int i0 = blockIdx.x * 1024 + threadIdx.x * 4;
  if (i0 + 3 < n) {
    int4 o = *(const int4*)(offs + i0);
    o.x += base; o.y += base; o.z += base; o.w += base;
    *(int4*)(offs + i0) = o;
  } else {
    for (int j = 0; j < 4; ++j)
      if (i0 + j < n) offs[i0 + j] += base;
  }
}

// ---------------------------------------------------------------------------
// csr_scatter: one block per bucket; per-node cursors in LDS.
// ---------------------------------------------------------------------------
__global__ __launch_bounds__(256) void csr_scatter(
    const int2* __restrict__ ebuf, const int* __restrict__ boffs,
    const int* __restrict__ bcnt, const int* __restrict__ offs,
    int* __restrict__ csr_src, int n_nodes) {
  __shared__ int cur[BGRAN];
  int b = blockIdx.x;
  int t = threadIdx.x;
  int node = b * BGRAN + t;
  cur[t] = (node < n_nodes) ? offs[node] : 0;
  __syncthreads();
  int beg = boffs[b];
  int cnt = bcnt[b];
  for (int j = t; j < cnt; j += 256) {
    int2 e = ebuf[beg + j];
    int p = atomicAdd(&cur[e.y & (BGRAN - 1)], 1);
    csr_src[p] = e.x;
  }
}

// ---------------------------------------------------------------------------
// k1: LDS-tiled GEMM. [n x 128] @ [128 x 128], cols = [W1_l | W1_r].
// y1 output stored as fp16 (halves the layer-1 gather traffic downstream).
// ---------------------------------------------------------------------------
#define BM 128
#define BK 32
__global__ __launch_bounds__(256, 4) void k1_proj(
    const float* __restrict__ x,
    const float* __restrict__ Wl,
    const float* __restrict__ Wr,
    const float* __restrict__ b1,
    __half* __restrict__ y1h,
    float* __restrict__ r1,
    int n_nodes) {
  __shared__ float XS[BK][BM];
  __shared__ float WS[BK][128];
  int tid = threadIdx.x;
  int tx = tid & 15;
  int ty = tid >> 4;
  int n0 = blockIdx.x * BM;

  float acc[8][8];
#pragma unroll
  for (int i = 0; i < 8; ++i)
#pragma unroll
    for (int j = 0; j < 8; ++j) acc[i][j] = 0.f;

  for (int kb = 0; kb < IN_F; kb += BK) {
    {
      int node = tid >> 3;
      int k4 = (tid & 7) * 4;
#pragma unroll
      for (int p = 0; p < 4; ++p) {
        int nn = node + p * 32;
        int gs = min(n0 + nn, n_nodes - 1);
        float4 v = *(const float4*)(x + (size_t)gs * IN_F + kb + k4);
        XS[k4 + 0][nn] = v.x;
        XS[k4 + 1][nn] = v.y;
        XS[k4 + 2][nn] = v.z;
        XS[k4 + 3][nn] = v.w;
      }
    }
    {
#pragma unroll
      for (int p = 0; p < 4; ++p) {
        int s = tid + p * 256;
        int k = s >> 5;
        int col = (s & 31) * 4;
        const float* sp = (col < 64) ? (Wl + (size_t)(kb + k) * HID_F + col)
                                     : (Wr + (size_t)(kb + k) * HID_F + (col - 64));
        *(float4*)&WS[k][col] = *(const float4*)sp;
      }
    }
    __syncthreads();
#pragma unroll 4
    for (int k = 0; k < BK; ++k) {
      float4 xa = *(const float4*)&XS[k][ty * 8];
      float4 xb = *(const float4*)&XS[k][ty * 8 + 4];
      float4 wa = *(const float4*)&WS[k][tx * 8];
      float4 wb = *(const float4*)&WS[k][tx * 8 + 4];
      float xs[8] = {xa.x, xa.y, xa.z, xa.w, xb.x, xb.y, xb.z, xb.w};
      float ws[8] = {wa.x, wa.y, wa.z, wa.w, wb.x, wb.y, wb.z, wb.w};
#pragma unroll
      for (int i = 0; i < 8; ++i)
#pragma unroll
        for (int j = 0; j < 8; ++j) acc[i][j] += xs[i] * ws[j];
    }
    __syncthreads();
  }

  int outb = tx * 8;
  bool isR = (outb >= HID_F);
  int ob = isR ? outb - HID_F : outb;
  if (isR) {
    float bb[8];
#pragma unroll
    for (int j = 0; j < 8; ++j) bb[j] = b1[ob + j];
#pragma unroll
    for (int i = 0; i < 8; ++i) {
      int node = n0 + ty * 8 + i;
      if (node < n_nodes) {
        float4 o0 = make_float4(acc[i][0] + bb[0], acc[i][1] + bb[1],
                                acc[i][2] + bb[2], acc[i][3] + bb[3]);
        float4 o1 = make_float4(acc[i][4] + bb[4], acc[i][5] + bb[5],
                                acc[i][6] + bb[6], acc[i][7] + bb[7]);
        *(float4*)(r1 + (size_t)node * HID_F + ob) = o0;
        *(float4*)(r1 + (size_t)node * HID_F + ob + 4) = o1;
      }
    }
  } else {
#pragma unroll
    for (int i = 0; i < 8; ++i) {
      int node = n0 + ty * 8 + i;
      if (node < n_nodes) {
        __half hh[8];
#pragma unroll
        for (int j = 0; j < 8; ++j) hh[j] = __float2half(acc[i][j]);
        *(uint4*)(y1h + (size_t)node * HID_F + ob) = *(uint4*)hh;  // 16B aligned
      }
    }
  }
}

// ---------------------------------------------------------------------------
// agg1_fused: one wave per dst node, lane = hidden feature.
// fp16 y1 gathers (half the bytes), fused epilogue, PLUS fused z = h @ W2_l
// (per-lane FMA + 64-lane butterfly reduction; lanes 0..7 store z).
// ---------------------------------------------------------------------------
__global__ __launch_bounds__(256) void agg1_fused(
    const __half* __restrict__ y1h,
    const float* __restrict__ r1,
    const int* __restrict__ deg_i,
    const int* __restrict__ offs,
    const int* __restrict__ csr_src,
    const float* __restrict__ mask,
    const float* __restrict__ W2l,
    float* __restrict__ h,
    float* __restrict__ z,
    int n_nodes) {
  int node = (blockIdx.x * blockDim.x + threadIdx.x) >> 6;
  int lane = threadIdx.x & 63;
  if (node >= n_nodes) return;
  int beg = offs[node];
  int d = deg_i[node];
  float acc = 0.f;
  int j = 0;
  for (; j + 4 <= d; j += 4) {
    int s0 = csr_src[beg + j + 0];
    int s1 = csr_src[beg + j + 1];
    int s2 = csr_src[beg + j + 2];
    int s3 = csr_src[beg + j + 3];
    float v0 = __half2float(y1h[(size_t)s0 * HID_F + lane]);
    float v1 = __half2float(y1h[(size_t)s1 * HID_F + lane]);
    float v2 = __half2float(y1h[(size_t)s2 * HID_F + lane]);
    float v3 = __half2float(y1h[(size_t)s3 * HID_F + lane]);
    acc += v0 + v1 + v2 + v3;
  }
  for (; j < d; ++j) {
    int s = csr_src[beg + j];
    acc += __half2float(y1h[(size_t)s * HID_F + lane]);
  }
  float dv = fmaxf((float)d, 1.0f);
  size_t o = (size_t)node * HID_F + lane;
  float v = acc / dv + r1[o];
  v = fmaxf(v, 0.0f);
  v = (mask[o] > 0.5f) ? v * 2.0f : 0.0f;
  h[o] = v;

  // fused z = h-row @ W2_l : lane holds h[lane]; W2l row `lane` (8 floats)
  float4 w0 = *(const float4*)(W2l + lane * OUT_F);
  float4 w1 = *(const float4*)(W2l + lane * OUT_F + 4);
  float zacc[8] = {v * w0.x, v * w0.y, v * w0.z, v * w0.w,
                   v * w1.x, v * w1.y, v * w1.z, v * w1.w};
#pragma unroll
  for (int dd = 32; dd >= 1; dd >>= 1) {
#pragma unroll
    for (int q = 0; q < 8; ++q) zacc[q] += __shfl_xor(zacc[q], dd);
  }
  if (lane < OUT_F) z[(size_t)node * OUT_F + lane] = zacc[lane];
}

// ---------------------------------------------------------------------------
// out_fused: one wave per batch element; layer-2 agg only at idx nodes.
// ---------------------------------------------------------------------------
__global__ __launch_bounds__(256) void out_fused(
    const int* __restrict__ idx,
    const float* __restrict__ z,
    const int* __restrict__ deg_i,
    const int* __restrict__ offs,
    const int* __restrict__ csr_src,
    const float* __restrict__ h,
    const float* __restrict__ W2r,
    const float* __restrict__ b2,
    float* __restrict__ out,
    int n_batch) {
  int b = (blockIdx.x * blockDim.x + threadIdx.x) >> 6;
  int lane = threadIdx.x & 63;
  if (b >= n_batch) return;
  int i = idx[b];
  int e8 = lane >> 3;
  int o = lane & 7;
  int beg = offs[i];
  int d = deg_i[i];
  float acc = 0.f;
  for (int j = e8; j < d; j += 8) {
    int s = csr_src[beg + j];
    acc += z[(size_t)s * OUT_F + o];
  }
  float dv = fmaxf((float)d, 1.0f);
  float v = acc / dv;
  const float* hr = h + (size_t)i * HID_F;
#pragma unroll
  for (int jj = 0; jj < 8; ++jj) {
    int k = e8 * 8 + jj;
    v += hr[k] * W2r[k * OUT_F + o];
  }
  v += __shfl_xor(v, 8);
  v += __shfl_xor(v, 16);
  v += __shfl_xor(v, 32);
  if (e8 == 0) out[(size_t)b * OUT_F + o] = v + b2[o];
}

extern "C" void kernel_launch(void* const* d_in, const int* in_sizes, int n_in,
                              void* d_out, int out_size, void* d_ws, size_t ws_size,
                              hipStream_t stream) {
  const float* x    = (const float*)d_in[0];
  const int*   ei   = (const int*)d_in[1];
  const int*   idx  = (const int*)d_in[2];
  const float* mask = (const float*)d_in[3];
  const float* W1l  = (const float*)d_in[4];
  const float* W1r  = (const float*)d_in[5];
  const float* b1   = (const float*)d_in[6];
  const float* W2l  = (const float*)d_in[7];
  const float* W2r  = (const float*)d_in[8];
  const float* b2   = (const float*)d_in[9];
  float* out = (float*)d_out;

  int n_nodes = in_sizes[0] / IN_F;
  int n_edges = in_sizes[1] / 2;
  int n_batch = in_sizes[2];
  const int* src = ei;
  const int* dst = ei + n_edges;

  // workspace layout; region A = union(y1h fp16 [N*64*2B], ebuf int2 [E*8B])
  char* ws = (char*)d_ws;
  size_t off = 0;
  size_t y1_bytes = (size_t)n_nodes * HID_F * sizeof(__half);
  size_t eb_bytes = (size_t)n_edges * sizeof(int2);
  size_t regA = (y1_bytes > eb_bytes) ? y1_bytes : eb_bytes;
  __half* y1h = (__half*)(ws + off);
  int2* ebuf  = (int2*)(ws + off); off += regA;
  float* r1 = (float*)(ws + off); off += (size_t)n_nodes * HID_F * 4;
  float* h  = (float*)(ws + off); off += (size_t)n_nodes * HID_F * 4;
  float* z  = (float*)(ws + off); off += (size_t)n_nodes * OUT_F * 4;
  int* deg_i   = (int*)(ws + off); off += (size_t)n_nodes * 4;
  int* offs    = (int*)(ws + off); off += (size_t)n_nodes * 4;
  int* csr_src = (int*)(ws + off); off += (size_t)n_edges * 4;
  int* blk_sums   = (int*)(ws + off); off += 256 * 4;
  int* bucket_cnt = (int*)(ws + off); off += 512 * 4;
  int* bucket_off = (int*)(ws + off); off += 512 * 4;
  int* bucket_cur = (int*)(ws + off); off += 512 * 4;

  int nbuk = (n_nodes + BGRAN - 1) / BGRAN;
  int nchunk = (n_edges + CHUNK - 1) / CHUNK;

  hipMemsetAsync(bucket_cnt, 0, 512 * sizeof(int), stream);

  // --- bucketed CSR build ---
  bucket_count<<<nchunk, 256, 0, stream>>>(dst, bucket_cnt, n_edges);
  bucket_scan<<<1, 512, 0, stream>>>(bucket_cnt, bucket_off, bucket_cur, nbuk);
  bucket_scatter<<<nchunk, 256, 0, stream>>>(src, dst, bucket_cur, ebuf, n_edges);
  deg_kernel<<<nbuk, 256, 0, stream>>>(ebuf, bucket_off, bucket_cnt, deg_i, n_nodes);
  int nblk = (n_nodes + 1023) / 1024;
  scan_local<<<nblk, 256, 0, stream>>>(deg_i, offs, blk_sums, n_nodes);
  scan_blk<<<1, 256, 0, stream>>>(blk_sums, nblk);
  scan_add<<<nblk, 256, 0, stream>>>(offs, blk_sums, n_nodes);
  csr_scatter<<<nbuk, 256, 0, stream>>>(ebuf, bucket_off, bucket_cnt, offs, csr_src, n_nodes);

  // --- layer 1 (+ fused z) ---
  k1_proj<<<(n_nodes + BM - 1) / BM, 256, 0, stream>>>(x, W1l, W1r, b1, y1h, r1, n_nodes);
  {
    long long th = (long long)n_nodes * HID_F;
    agg1_fused<<<(int)((th + 255) / 256), 256, 0, stream>>>(
        y1h, r1, deg_i, offs, csr_src, mask, W2l, h, z, n_nodes);
  }

  // --- layer 2 output ---
  {
    long long th = (long long)n_batch * 64;
    out_fused<<<(int)((th + 255) / 256), 256, 0, stream>>>(idx, z, deg_i, offs, csr_src, h, W2r, b2, out, n_batch);
  }
}

// Round 7
// 310.509 us; speedup vs baseline: 7.1222x; 1.0381x over previous
//
#include <hip/hip_runtime.h>
#include <hip/hip_fp16.h>

#define IN_F 128
#define HID_F 64
#define OUT_F 8

// Bucketed CSR build: bucket = dst >> 8 (256 nodes per bucket).
#define BSHIFT 8
#define BGRAN 256
#define CHUNK 4096
#define EPT (CHUNK / 256)

// ---------------------------------------------------------------------------
// bucket_count: per-block LDS histogram of dst>>8, one global atomic/bucket.
// ---------------------------------------------------------------------------
__global__ __launch_bounds__(256) void bucket_count(
    const int* __restrict__ dst, int* __restrict__ bucket_cnt, int n_edges) {
  __shared__ int hist[512];
  int t = threadIdx.x;
  for (int i = t; i < 512; i += 256) hist[i] = 0;
  __syncthreads();
  int e0 = blockIdx.x * CHUNK;
#pragma unroll
  for (int k = 0; k < EPT; ++k) {
    int e = e0 + k * 256 + t;
    if (e < n_edges) atomicAdd(&hist[dst[e] >> BSHIFT], 1);
  }
  __syncthreads();
  for (int i = t; i < 512; i += 256) {
    int c = hist[i];
    if (c) atomicAdd(&bucket_cnt[i], c);
  }
}

// ---------------------------------------------------------------------------
// bucket_scan: exclusive scan of bucket counts (nbuk <= 512), one block.
// ---------------------------------------------------------------------------
__global__ __launch_bounds__(512) void bucket_scan(
    const int* __restrict__ cnt, int* __restrict__ boffs,
    int* __restrict__ bcur, int nbuk) {
  __shared__ int s[512];
  int t = threadIdx.x;
  s[t] = (t < nbuk) ? cnt[t] : 0;
  __syncthreads();
  for (int d = 1; d < 512; d <<= 1) {
    int v = 0;
    if (t >= d) v = s[t - d];
    __syncthreads();
    if (t >= d) s[t] += v;
    __syncthreads();
  }
  if (t < nbuk) {
    int e = (t == 0) ? 0 : s[t - 1];
    boffs[t] = e;
    bcur[t] = e;
  }
}

// ---------------------------------------------------------------------------
// bucket_scatter: reserve contiguous per-bucket runs, write packed (src,dst).
// ---------------------------------------------------------------------------
__global__ __launch_bounds__(256) void bucket_scatter(
    const int* __restrict__ src, const int* __restrict__ dst,
    int* __restrict__ bcur, int2* __restrict__ ebuf, int n_edges) {
  __shared__ int hist[512];
  __shared__ int base[512];
  int t = threadIdx.x;
  for (int i = t; i < 512; i += 256) hist[i] = 0;
  __syncthreads();
  int e0 = blockIdx.x * CHUNK;
  int2 ed[EPT];
  int bk[EPT];
#pragma unroll
  for (int k = 0; k < EPT; ++k) {
    int e = e0 + k * 256 + t;
    if (e < n_edges) {
      ed[k].x = src[e];
      ed[k].y = dst[e];
      bk[k] = ed[k].y >> BSHIFT;
      atomicAdd(&hist[bk[k]], 1);
    } else {
      bk[k] = -1;
    }
  }
  __syncthreads();
  for (int i = t; i < 512; i += 256) {
    int c = hist[i];
    base[i] = c ? atomicAdd(&bcur[i], c) : 0;
  }
  __syncthreads();
  for (int i = t; i < 512; i += 256) hist[i] = 0;
  __syncthreads();
#pragma unroll
  for (int k = 0; k < EPT; ++k) {
    if (bk[k] >= 0) {
      int r = atomicAdd(&hist[bk[k]], 1);
      ebuf[base[bk[k]] + r] = ed[k];
    }
  }
}

// ---------------------------------------------------------------------------
// deg_kernel: one block per bucket; LDS histogram; coalesced deg_i writes.
// ---------------------------------------------------------------------------
__global__ __launch_bounds__(256) void deg_kernel(
    const int2* __restrict__ ebuf, const int* __restrict__ boffs,
    const int* __restrict__ bcnt, int* __restrict__ deg_i, int n_nodes) {
  __shared__ int hist[BGRAN];
  int b = blockIdx.x;
  int t = threadIdx.x;
  hist[t] = 0;
  __syncthreads();
  int beg = boffs[b];
  int cnt = bcnt[b];
  for (int j = t; j < cnt; j += 256)
    atomicAdd(&hist[ebuf[beg + j].y & (BGRAN - 1)], 1);
  __syncthreads();
  int node = b * BGRAN + t;
  if (node < n_nodes) deg_i[node] = hist[t];
}

// ---------------------------------------------------------------------------
// device-wide exclusive scan over deg_i (3 phases)
// ---------------------------------------------------------------------------
__global__ __launch_bounds__(256) void scan_local(
    const int* __restrict__ deg_i, int* __restrict__ offs,
    int* __restrict__ blk_sums, int n) {
  __shared__ int tsum[256];
  int t = threadIdx.x;
  int i0 = blockIdx.x * 1024 + t * 4;
  int v0 = 0, v1 = 0, v2 = 0, v3 = 0;
  if (i0 + 3 < n) {
    int4 d = *(const int4*)(deg_i + i0);
    v0 = d.x; v1 = d.y; v2 = d.z; v3 = d.w;
  } else {
    if (i0 + 0 < n) v0 = deg_i[i0 + 0];
    if (i0 + 1 < n) v1 = deg_i[i0 + 1];
    if (i0 + 2 < n) v2 = deg_i[i0 + 2];
    if (i0 + 3 < n) v3 = deg_i[i0 + 3];
  }
  tsum[t] = v0 + v1 + v2 + v3;
  __syncthreads();
  for (int d = 1; d < 256; d <<= 1) {
    int x = 0;
    if (t >= d) x = tsum[t - d];
    __syncthreads();
    if (t >= d) tsum[t] += x;
    __syncthreads();
  }
  if (t == 255) blk_sums[blockIdx.x] = tsum[255];
  int run = (t == 0) ? 0 : tsum[t - 1];
  int o0 = run, o1 = o0 + v0, o2 = o1 + v1, o3 = o2 + v2;
  if (i0 + 3 < n) {
    *(int4*)(offs + i0) = make_int4(o0, o1, o2, o3);
  } else {
    if (i0 + 0 < n) offs[i0 + 0] = o0;
    if (i0 + 1 < n) offs[i0 + 1] = o1;
    if (i0 + 2 < n) offs[i0 + 2] = o2;
    if (i0 + 3 < n) offs[i0 + 3] = o3;
  }
}

__global__ __launch_bounds__(256) void scan_blk(
    int* __restrict__ blk_sums, int nblk) {
  __shared__ int s[256];
  int t = threadIdx.x;
  s[t] = (t < nblk) ? blk_sums[t] : 0;
  __syncthreads();
  for (int d = 1; d < 256; d <<= 1) {
    int x = 0;
    if (t >= d) x = s[t - d];
    __syncthreads();
    if (t >= d) s[t] += x;
    __syncthreads();
  }
  if (t < nblk) blk_sums[t] = (t == 0) ? 0 : s[t - 1];
}

__global__ __launch_bounds__(256) void scan_add(
    int* __restrict__ offs, const int* __restrict__ blk_sums, int n) {
  int base = blk_sums[blockIdx.x];
  int i0 = blockIdx.x * 1024 + threadIdx.x * 4;
  if (i0 + 3 < n) {
    int4 o = *(const int4*)(offs + i0);
    o.x += base; o.y += base; o.z += base; o.w += base;
    *(int4*)(offs + i0) = o;
  } else {
    for (int j = 0; j < 4; ++j)
      if (i0 + j < n) offs[i0 + j] += base;
  }
}

// ---------------------------------------------------------------------------
// csr_scatter: one block per bucket; per-node cursors in LDS.
// ---------------------------------------------------------------------------
__global__ __launch_bounds__(256) void csr_scatter(
    const int2* __restrict__ ebuf, const int* __restrict__ boffs,
    const int* __restrict__ bcnt, const int* __restrict__ offs,
    int* __restrict__ csr_src, int n_nodes) {
  __shared__ int cur[BGRAN];
  int b = blockIdx.x;
  int t = threadIdx.x;
  int node = b * BGRAN + t;
  cur[t] = (node < n_nodes) ? offs[node] : 0;
  __syncthreads();
  int beg = boffs[b];
  int cnt = bcnt[b];
  for (int j = t; j < cnt; j += 256) {
    int2 e = ebuf[beg + j];
    int p = atomicAdd(&cur[e.y & (BGRAN - 1)], 1);
    csr_src[p] = e.x;
  }
}

// ---------------------------------------------------------------------------
// k1: LDS-tiled GEMM. [n x 128] @ [128 x 128], cols = [W1_l | W1_r].
// y1 output stored as fp16 (halves layer-1 gather traffic downstream).
// ---------------------------------------------------------------------------
#define BM 128
#define BK 32
__global__ __launch_bounds__(256, 4) void k1_proj(
    const float* __restrict__ x,
    const float* __restrict__ Wl,
    const float* __restrict__ Wr,
    const float* __restrict__ b1,
    __half* __restrict__ y1h,
    float* __restrict__ r1,
    int n_nodes) {
  __shared__ float XS[BK][BM];
  __shared__ float WS[BK][128];
  int tid = threadIdx.x;
  int tx = tid & 15;
  int ty = tid >> 4;
  int n0 = blockIdx.x * BM;

  float acc[8][8];
#pragma unroll
  for (int i = 0; i < 8; ++i)
#pragma unroll
    for (int j = 0; j < 8; ++j) acc[i][j] = 0.f;

  for (int kb = 0; kb < IN_F; kb += BK) {
    {
      int node = tid >> 3;
      int k4 = (tid & 7) * 4;
#pragma unroll
      for (int p = 0; p < 4; ++p) {
        int nn = node + p * 32;
        int gs = min(n0 + nn, n_nodes - 1);
        float4 v = *(const float4*)(x + (size_t)gs * IN_F + kb + k4);
        XS[k4 + 0][nn] = v.x;
        XS[k4 + 1][nn] = v.y;
        XS[k4 + 2][nn] = v.z;
        XS[k4 + 3][nn] = v.w;
      }
    }
    {
#pragma unroll
      for (int p = 0; p < 4; ++p) {
        int s = tid + p * 256;
        int k = s >> 5;
        int col = (s & 31) * 4;
        const float* sp = (col < 64) ? (Wl + (size_t)(kb + k) * HID_F + col)
                                     : (Wr + (size_t)(kb + k) * HID_F + (col - 64));
        *(float4*)&WS[k][col] = *(const float4*)sp;
      }
    }
    __syncthreads();
#pragma unroll 4
    for (int k = 0; k < BK; ++k) {
      float4 xa = *(const float4*)&XS[k][ty * 8];
      float4 xb = *(const float4*)&XS[k][ty * 8 + 4];
      float4 wa = *(const float4*)&WS[k][tx * 8];
      float4 wb = *(const float4*)&WS[k][tx * 8 + 4];
      float xs[8] = {xa.x, xa.y, xa.z, xa.w, xb.x, xb.y, xb.z, xb.w};
      float ws[8] = {wa.x, wa.y, wa.z, wa.w, wb.x, wb.y, wb.z, wb.w};
#pragma unroll
      for (int i = 0; i < 8; ++i)
#pragma unroll
        for (int j = 0; j < 8; ++j) acc[i][j] += xs[i] * ws[j];
    }
    __syncthreads();
  }

  int outb = tx * 8;
  bool isR = (outb >= HID_F);
  int ob = isR ? outb - HID_F : outb;
  if (isR) {
    float bb[8];
#pragma unroll
    for (int j = 0; j < 8; ++j) bb[j] = b1[ob + j];
#pragma unroll
    for (int i = 0; i < 8; ++i) {
      int node = n0 + ty * 8 + i;
      if (node < n_nodes) {
        float4 o0 = make_float4(acc[i][0] + bb[0], acc[i][1] + bb[1],
                                acc[i][2] + bb[2], acc[i][3] + bb[3]);
        float4 o1 = make_float4(acc[i][4] + bb[4], acc[i][5] + bb[5],
                                acc[i][6] + bb[6], acc[i][7] + bb[7]);
        *(float4*)(r1 + (size_t)node * HID_F + ob) = o0;
        *(float4*)(r1 + (size_t)node * HID_F + ob + 4) = o1;
      }
    }
  } else {
#pragma unroll
    for (int i = 0; i < 8; ++i) {
      int node = n0 + ty * 8 + i;
      if (node < n_nodes) {
        __half hh[8];
#pragma unroll
        for (int j = 0; j < 8; ++j) hh[j] = __float2half(acc[i][j]);
        *(uint4*)(y1h + (size_t)node * HID_F + ob) = *(uint4*)hh;
      }
    }
  }
}

// ---------------------------------------------------------------------------
// agg1_fused: one wave per dst node. Dual-edge half2 gathers:
// lane = (edge-parity half, feature-pair fp). Each 4B half2 load instruction
// covers TWO edges (32 lanes x 4B = one 128B row per half). Indices come in
// as wave-uniform int4 (4 edges per load). shfl_xor(32) merges the halves.
// ---------------------------------------------------------------------------
__global__ __launch_bounds__(256) void agg1_fused(
    const __half* __restrict__ y1h,
    const float* __restrict__ r1,
    const int* __restrict__ deg_i,
    const int* __restrict__ offs,
    const int* __restrict__ csr_src,
    const float* __restrict__ mask,
    float* __restrict__ h,
    int n_nodes) {
  int node = (blockIdx.x * blockDim.x + threadIdx.x) >> 6;
  int lane = threadIdx.x & 63;
  if (node >= n_nodes) return;
  int half = lane >> 5;          // which edge of each pair
  int fp = lane & 31;            // feature pair: features 2fp, 2fp+1
  int beg = offs[node];
  int d = deg_i[node];
  const int* cp = csr_src + beg;
  float ax = 0.f, ay = 0.f;
  int j = 0;
  for (; j + 8 <= d; j += 8) {
    int4 ia = *(const int4*)(cp + j);      // edges j .. j+3 (wave-uniform)
    int4 ib = *(const int4*)(cp + j + 4);  // edges j+4 .. j+7
    int s0 = half ? ia.y : ia.x;
    int s1 = half ? ia.w : ia.z;
    int s2 = half ? ib.y : ib.x;
    int s3 = half ? ib.w : ib.z;
    __half2 g0 = *(const __half2*)(y1h + (size_t)s0 * HID_F + fp * 2);
    __half2 g1 = *(const __half2*)(y1h + (size_t)s1 * HID_F + fp * 2);
    __half2 g2 = *(const __half2*)(y1h + (size_t)s2 * HID_F + fp * 2);
    __half2 g3 = *(const __half2*)(y1h + (size_t)s3 * HID_F + fp * 2);
    float2 f0 = __half22float2(g0);
    float2 f1 = __half22float2(g1);
    float2 f2 = __half22float2(g2);
    float2 f3 = __half22float2(g3);
    ax += (f0.x + f1.x) + (f2.x + f3.x);
    ay += (f0.y + f1.y) + (f2.y + f3.y);
  }
  for (; j < d; j += 2) {
    int e = j + half;
    if (e < d) {
      int s = cp[e];
      float2 f = __half22float2(*(const __half2*)(y1h + (size_t)s * HID_F + fp * 2));
      ax += f.x;
      ay += f.y;
    }
  }
  // merge edge-parity halves (both halves end with the full sum)
  ax += __shfl_xor(ax, 32);
  ay += __shfl_xor(ay, 32);
  if (half == 0) {
    float dv = fmaxf((float)d, 1.0f);
    size_t o = (size_t)node * HID_F + fp * 2;
    float2 rr = *(const float2*)(r1 + o);
    float2 mm = *(const float2*)(mask + o);
    float vx = ax / dv + rr.x;
    float vy = ay / dv + rr.y;
    vx = fmaxf(vx, 0.f);
    vy = fmaxf(vy, 0.f);
    vx = (mm.x > 0.5f) ? vx * 2.f : 0.f;
    vy = (mm.y > 0.5f) ? vy * 2.f : 0.f;
    *(float2*)(h + o) = make_float2(vx, vy);
  }
}

// ---------------------------------------------------------------------------
// k3b: z = h @ W2_l ([N,8]). One node per thread; W2_l in LDS.
// ---------------------------------------------------------------------------
__global__ __launch_bounds__(256) void k3b_z(
    const float* __restrict__ h,
    const float* __restrict__ W2l,
    float* __restrict__ z,
    int n_nodes) {
  __shared__ float WS[HID_F][OUT_F];
  int tid = threadIdx.x;
  if (tid < 128) {
    float4 w = *(const float4*)(W2l + tid * 4);
    *(float4*)&WS[tid >> 1][(tid & 1) * 4] = w;
  }
  __syncthreads();
  int node = blockIdx.x * blockDim.x + tid;
  if (node >= n_nodes) return;
  const float* hr = h + (size_t)node * HID_F;
  float acc[8] = {0, 0, 0, 0, 0, 0, 0, 0};
  for (int k = 0; k < HID_F; k += 4) {
    float4 hv = *(const float4*)(hr + k);
    float hh[4] = {hv.x, hv.y, hv.z, hv.w};
#pragma unroll
    for (int j = 0; j < 4; ++j) {
      float4 w0 = *(const float4*)&WS[k + j][0];
      float4 w1 = *(const float4*)&WS[k + j][4];
      acc[0] += hh[j] * w0.x; acc[1] += hh[j] * w0.y;
      acc[2] += hh[j] * w0.z; acc[3] += hh[j] * w0.w;
      acc[4] += hh[j] * w1.x; acc[5] += hh[j] * w1.y;
      acc[6] += hh[j] * w1.z; acc[7] += hh[j] * w1.w;
    }
  }
  float* zp = z + (size_t)node * OUT_F;
  *(float4*)(zp + 0) = make_float4(acc[0], acc[1], acc[2], acc[3]);
  *(float4*)(zp + 4) = make_float4(acc[4], acc[5], acc[6], acc[7]);
}

// ---------------------------------------------------------------------------
// out_fused: one wave per batch element; layer-2 agg only at idx nodes.
// ---------------------------------------------------------------------------
__global__ __launch_bounds__(256) void out_fused(
    const int* __restrict__ idx,
    const float* __restrict__ z,
    const int* __restrict__ deg_i,
    const int* __restrict__ offs,
    const int* __restrict__ csr_src,
    const float* __restrict__ h,
    const float* __restrict__ W2r,
    const float* __restrict__ b2,
    float* __restrict__ out,
    int n_batch) {
  int b = (blockIdx.x * blockDim.x + threadIdx.x) >> 6;
  int lane = threadIdx.x & 63;
  if (b >= n_batch) return;
  int i = idx[b];
  int e8 = lane >> 3;
  int o = lane & 7;
  int beg = offs[i];
  int d = deg_i[i];
  float acc = 0.f;
  for (int j = e8; j < d; j += 8) {
    int s = csr_src[beg + j];
    acc += z[(size_t)s * OUT_F + o];
  }
  float dv = fmaxf((float)d, 1.0f);
  float v = acc / dv;
  const float* hr = h + (size_t)i * HID_F;
#pragma unroll
  for (int jj = 0; jj < 8; ++jj) {
    int k = e8 * 8 + jj;
    v += hr[k] * W2r[k * OUT_F + o];
  }
  v += __shfl_xor(v, 8);
  v += __shfl_xor(v, 16);
  v += __shfl_xor(v, 32);
  if (e8 == 0) out[(size_t)b * OUT_F + o] = v + b2[o];
}

extern "C" void kernel_launch(void* const* d_in, const int* in_sizes, int n_in,
                              void* d_out, int out_size, void* d_ws, size_t ws_size,
                              hipStream_t stream) {
  const float* x    = (const float*)d_in[0];
  const int*   ei   = (const int*)d_in[1];
  const int*   idx  = (const int*)d_in[2];
  const float* mask = (const float*)d_in[3];
  const float* W1l  = (const float*)d_in[4];
  const float* W1r  = (const float*)d_in[5];
  const float* b1   = (const float*)d_in[6];
  const float* W2l  = (const float*)d_in[7];
  const float* W2r  = (const float*)d_in[8];
  const float* b2   = (const float*)d_in[9];
  float* out = (float*)d_out;

  int n_nodes = in_sizes[0] / IN_F;
  int n_edges = in_sizes[1] / 2;
  int n_batch = in_sizes[2];
  const int* src = ei;
  const int* dst = ei + n_edges;

  // workspace layout; region A = union(y1h fp16 [N*64*2B], ebuf int2 [E*8B])
  char* ws = (char*)d_ws;
  size_t off = 0;
  size_t y1_bytes = (size_t)n_nodes * HID_F * sizeof(__half);
  size_t eb_bytes = (size_t)n_edges * sizeof(int2);
  size_t regA = (y1_bytes > eb_bytes) ? y1_bytes : eb_bytes;
  __half* y1h = (__half*)(ws + off);
  int2* ebuf  = (int2*)(ws + off); off += regA;
  float* r1 = (float*)(ws + off); off += (size_t)n_nodes * HID_F * 4;
  float* h  = (float*)(ws + off); off += (size_t)n_nodes * HID_F * 4;
  float* z  = (float*)(ws + off); off += (size_t)n_nodes * OUT_F * 4;
  int* deg_i   = (int*)(ws + off); off += (size_t)n_nodes * 4;
  int* offs    = (int*)(ws + off); off += (size_t)n_nodes * 4;
  int* csr_src = (int*)(ws + off); off += (size_t)n_edges * 4;
  int* blk_sums   = (int*)(ws + off); off += 256 * 4;
  int* bucket_cnt = (int*)(ws + off); off += 512 * 4;
  int* bucket_off = (int*)(ws + off); off += 512 * 4;
  int* bucket_cur = (int*)(ws + off); off += 512 * 4;

  int nbuk = (n_nodes + BGRAN - 1) / BGRAN;
  int nchunk = (n_edges + CHUNK - 1) / CHUNK;

  hipMemsetAsync(bucket_cnt, 0, 512 * sizeof(int), stream);

  // --- bucketed CSR build ---
  bucket_count<<<nchunk, 256, 0, stream>>>(dst, bucket_cnt, n_edges);
  bucket_scan<<<1, 512, 0, stream>>>(bucket_cnt, bucket_off, bucket_cur, nbuk);
  bucket_scatter<<<nchunk, 256, 0, stream>>>(src, dst, bucket_cur, ebuf, n_edges);
  deg_kernel<<<nbuk, 256, 0, stream>>>(ebuf, bucket_off, bucket_cnt, deg_i, n_nodes);
  int nblk = (n_nodes + 1023) / 1024;
  scan_local<<<nblk, 256, 0, stream>>>(deg_i, offs, blk_sums, n_nodes);
  scan_blk<<<1, 256, 0, stream>>>(blk_sums, nblk);
  scan_add<<<nblk, 256, 0, stream>>>(offs, blk_sums, n_nodes);
  csr_scatter<<<nbuk, 256, 0, stream>>>(ebuf, bucket_off, bucket_cnt, offs, csr_src, n_nodes);

  // --- layer 1 ---
  k1_proj<<<(n_nodes + BM - 1) / BM, 256, 0, stream>>>(x, W1l, W1r, b1, y1h, r1, n_nodes);
  {
    long long th = (long long)n_nodes * HID_F;
    agg1_fused<<<(int)((th + 255) / 256), 256, 0, stream>>>(
        y1h, r1, deg_i, offs, csr_src, mask, h, n_nodes);
  }

  // --- layer 2 ---
  k3b_z<<<(n_nodes + 255) / 256, 256, 0, stream>>>(h, W2l, z, n_nodes);
  {
    long long th = (long long)n_batch * 64;
    out_fused<<<(int)((th + 255) / 256), 256, 0, stream>>>(idx, z, deg_i, offs, csr_src, h, W2r, b2, out, n_batch);
  }
}

// Round 8
// 279.026 us; speedup vs baseline: 7.9258x; 1.1128x over previous
//
#include <hip/hip_runtime.h>
#include <hip/hip_fp16.h>

#define IN_F 128
#define HID_F 64
#define OUT_F 8

// Bucketed CSR build: bucket = dst >> 8 (256 nodes/bucket), fixed-capacity
// bucket runs (CAP >> 30 sigma above the E/nbuk=4096 mean) so the count+scan
// pre-passes are unnecessary.
#define BSHIFT 8
#define BGRAN 256
#define BCAP 6144
#define CHUNK 4096
#define EPT (CHUNK / 256)

#if defined(__has_builtin)
#if __has_builtin(__builtin_amdgcn_fdot2)
#define HAS_FDOT2 1
#endif
#endif

typedef _Float16 h2v __attribute__((ext_vector_type(2)));

// ---------------------------------------------------------------------------
// init_bcur: bucket cursors at fixed-capacity bases.
// ---------------------------------------------------------------------------
__global__ __launch_bounds__(512) void init_bcur(int* __restrict__ bcur) {
  bcur[threadIdx.x] = (int)threadIdx.x * BCAP;
}

// ---------------------------------------------------------------------------
// bucket_scatter: per-chunk LDS histogram -> one global reserve per bucket ->
// write packed (src,dst) grouped by bucket (near-full-line writes).
// ---------------------------------------------------------------------------
__global__ __launch_bounds__(256) void bucket_scatter(
    const int* __restrict__ src, const int* __restrict__ dst,
    int* __restrict__ bcur, int2* __restrict__ ebuf, int n_edges) {
  __shared__ int hist[512];
  __shared__ int base[512];
  int t = threadIdx.x;
  for (int i = t; i < 512; i += 256) hist[i] = 0;
  __syncthreads();
  int e0 = blockIdx.x * CHUNK;
  int2 ed[EPT];
  int bk[EPT];
#pragma unroll
  for (int k = 0; k < EPT; ++k) {
    int e = e0 + k * 256 + t;
    if (e < n_edges) {
      ed[k].x = src[e];
      ed[k].y = dst[e];
      bk[k] = ed[k].y >> BSHIFT;
      atomicAdd(&hist[bk[k]], 1);
    } else {
      bk[k] = -1;
    }
  }
  __syncthreads();
  for (int i = t; i < 512; i += 256) {
    int c = hist[i];
    base[i] = c ? atomicAdd(&bcur[i], c) : 0;
  }
  __syncthreads();
  for (int i = t; i < 512; i += 256) hist[i] = 0;
  __syncthreads();
#pragma unroll
  for (int k = 0; k < EPT; ++k) {
    if (bk[k] >= 0) {
      int r = atomicAdd(&hist[bk[k]], 1);
      ebuf[base[bk[k]] + r] = ed[k];
    }
  }
}

// ---------------------------------------------------------------------------
// deg_kernel: one block per bucket; LDS histogram; coalesced deg_i writes.
// ---------------------------------------------------------------------------
__global__ __launch_bounds__(256) void deg_kernel(
    const int2* __restrict__ ebuf, const int* __restrict__ bcur,
    int* __restrict__ deg_i, int n_nodes) {
  __shared__ int hist[BGRAN];
  int b = blockIdx.x;
  int t = threadIdx.x;
  hist[t] = 0;
  __syncthreads();
  int beg = b * BCAP;
  int cnt = bcur[b] - beg;
  for (int j = t; j < cnt; j += 256)
    atomicAdd(&hist[ebuf[beg + j].y & (BGRAN - 1)], 1);
  __syncthreads();
  int node = b * BGRAN + t;
  if (node < n_nodes) deg_i[node] = hist[t];
}

// ---------------------------------------------------------------------------
// device-wide exclusive scan over deg_i (local + block-total phases; the
// add-base phase is folded into csr_scatter since a bucket's 256 nodes all
// share one scan-block: base = blk_sums[b>>2]).
// ---------------------------------------------------------------------------
__global__ __launch_bounds__(256) void scan_local(
    const int* __restrict__ deg_i, int* __restrict__ offs_l,
    int* __restrict__ blk_sums, int n) {
  __shared__ int tsum[256];
  int t = threadIdx.x;
  int i0 = blockIdx.x * 1024 + t * 4;
  int v0 = 0, v1 = 0, v2 = 0, v3 = 0;
  if (i0 + 3 < n) {
    int4 d = *(const int4*)(deg_i + i0);
    v0 = d.x; v1 = d.y; v2 = d.z; v3 = d.w;
  } else {
    if (i0 + 0 < n) v0 = deg_i[i0 + 0];
    if (i0 + 1 < n) v1 = deg_i[i0 + 1];
    if (i0 + 2 < n) v2 = deg_i[i0 + 2];
    if (i0 + 3 < n) v3 = deg_i[i0 + 3];
  }
  tsum[t] = v0 + v1 + v2 + v3;
  __syncthreads();
  for (int d = 1; d < 256; d <<= 1) {
    int x = 0;
    if (t >= d) x = tsum[t - d];
    __syncthreads();
    if (t >= d) tsum[t] += x;
    __syncthreads();
  }
  if (t == 255) blk_sums[blockIdx.x] = tsum[255];
  int run = (t == 0) ? 0 : tsum[t - 1];
  int o0 = run, o1 = o0 + v0, o2 = o1 + v1, o3 = o2 + v2;
  if (i0 + 3 < n) {
    *(int4*)(offs_l + i0) = make_int4(o0, o1, o2, o3);
  } else {
    if (i0 + 0 < n) offs_l[i0 + 0] = o0;
    if (i0 + 1 < n) offs_l[i0 + 1] = o1;
    if (i0 + 2 < n) offs_l[i0 + 2] = o2;
    if (i0 + 3 < n) offs_l[i0 + 3] = o3;
  }
}

__global__ __launch_bounds__(256) void scan_blk(
    int* __restrict__ blk_sums, int nblk) {
  __shared__ int s[256];
  int t = threadIdx.x;
  s[t] = (t < nblk) ? blk_sums[t] : 0;
  __syncthreads();
  for (int d = 1; d < 256; d <<= 1) {
    int x = 0;
    if (t >= d) x = s[t - d];
    __syncthreads();
    if (t >= d) s[t] += x;
    __syncthreads();
  }
  if (t < nblk) blk_sums[t] = (t == 0) ? 0 : s[t - 1];
}

// ---------------------------------------------------------------------------
// csr_scatter: one block per bucket; finalizes offs (local+base) and scatters
// src ids within the bucket's ~16 KB csr window (single-XCD dirty lines).
// ---------------------------------------------------------------------------
__global__ __launch_bounds__(256) void csr_scatter(
    const int2* __restrict__ ebuf, const int* __restrict__ bcur,
    const int* __restrict__ offs_l, const int* __restrict__ blk_sums,
    int* __restrict__ offs_f, int* __restrict__ csr_src, int n_nodes) {
  __shared__ int cur[BGRAN];
  int b = blockIdx.x;
  int t = threadIdx.x;
  int node = b * BGRAN + t;
  int base = blk_sums[b >> 2];
  if (node < n_nodes) {
    int o = offs_l[node] + base;
    offs_f[node] = o;
    cur[t] = o;
  } else {
    cur[t] = 0;
  }
  __syncthreads();
  int beg = b * BCAP;
  int cnt = bcur[b] - beg;
  for (int j = t; j < cnt; j += 256) {
    int2 e = ebuf[beg + j];
    int p = atomicAdd(&cur[e.y & (BGRAN - 1)], 1);
    csr_src[p] = e.x;
  }
}

// ---------------------------------------------------------------------------
// k1: LDS-tiled GEMM with packed-f16 dot2 inner loop.
// [n x 128] @ [128 x 128], cols = [W1_l | W1_r]. y1 stored fp16.
// ---------------------------------------------------------------------------
#define BM 128
#define BK 32
__global__ __launch_bounds__(256, 4) void k1_proj(
    const float* __restrict__ x,
    const float* __restrict__ Wl,
    const float* __restrict__ Wr,
    const float* __restrict__ b1,
    __half* __restrict__ y1h,
    float* __restrict__ r1,
    int n_nodes) {
  __shared__ h2v XS2[BK / 2][BM];   // [kp][node], 8 KB
  __shared__ h2v WS2[BK / 2][128];  // [kp][out],  8 KB
  int tid = threadIdx.x;
  int tx = tid & 15;
  int ty = tid >> 4;
  int n0 = blockIdx.x * BM;

  float acc[8][8];
#pragma unroll
  for (int i = 0; i < 8; ++i)
#pragma unroll
    for (int j = 0; j < 8; ++j) acc[i][j] = 0.f;

  for (int kb = 0; kb < IN_F; kb += BK) {
    // stage X tile (transposed, f16-packed): 128 nodes x 16 k-pairs
    {
      int nn0 = tid >> 3;
      int k4 = (tid & 7) * 4;
      int kp0 = (tid & 7) * 2;
#pragma unroll
      for (int p = 0; p < 4; ++p) {
        int nn = nn0 + p * 32;
        int gs = min(n0 + nn, n_nodes - 1);
        float4 v = *(const float4*)(x + (size_t)gs * IN_F + kb + k4);
        XS2[kp0][nn] = h2v{(_Float16)v.x, (_Float16)v.y};
        XS2[kp0 + 1][nn] = h2v{(_Float16)v.z, (_Float16)v.w};
      }
    }
    // stage W tile: 16 k-pairs x 128 outs (L | R), pack rows k,k+1
    {
#pragma unroll
      for (int p = 0; p < 2; ++p) {
        int s = tid + p * 256;         // 512 slots: kp (16) x col4 (32)
        int kp = s >> 5;
        int col = (s & 31) * 4;
        int k0 = kb + kp * 2;
        const float* pa = (col < 64) ? (Wl + (size_t)k0 * HID_F + col)
                                     : (Wr + (size_t)k0 * HID_F + (col - 64));
        const float* pb = (col < 64) ? (Wl + (size_t)(k0 + 1) * HID_F + col)
                                     : (Wr + (size_t)(k0 + 1) * HID_F + (col - 64));
        float4 wa = *(const float4*)pa;
        float4 wb = *(const float4*)pb;
        WS2[kp][col + 0] = h2v{(_Float16)wa.x, (_Float16)wb.x};
        WS2[kp][col + 1] = h2v{(_Float16)wa.y, (_Float16)wb.y};
        WS2[kp][col + 2] = h2v{(_Float16)wa.z, (_Float16)wb.z};
        WS2[kp][col + 3] = h2v{(_Float16)wa.w, (_Float16)wb.w};
      }
    }
    __syncthreads();
#pragma unroll 4
    for (int kp = 0; kp < BK / 2; ++kp) {
      h2v xv[8], wv[8];
#pragma unroll
      for (int i = 0; i < 8; ++i) xv[i] = XS2[kp][ty * 8 + i];
#pragma unroll
      for (int j = 0; j < 8; ++j) wv[j] = WS2[kp][tx * 8 + j];
#pragma unroll
      for (int i = 0; i < 8; ++i)
#pragma unroll
        for (int j = 0; j < 8; ++j) {
#ifdef HAS_FDOT2
          acc[i][j] = __builtin_amdgcn_fdot2(xv[i], wv[j], acc[i][j], false);
#else
          acc[i][j] += (float)xv[i][0] * (float)wv[j][0] +
                       (float)xv[i][1] * (float)wv[j][1];
#endif
        }
    }
    __syncthreads();
  }

  int outb = tx * 8;
  bool isR = (outb >= HID_F);
  int ob = isR ? outb - HID_F : outb;
  if (isR) {
    float bb[8];
#pragma unroll
    for (int j = 0; j < 8; ++j) bb[j] = b1[ob + j];
#pragma unroll
    for (int i = 0; i < 8; ++i) {
      int node = n0 + ty * 8 + i;
      if (node < n_nodes) {
        float4 o0 = make_float4(acc[i][0] + bb[0], acc[i][1] + bb[1],
                                acc[i][2] + bb[2], acc[i][3] + bb[3]);
        float4 o1 = make_float4(acc[i][4] + bb[4], acc[i][5] + bb[5],
                                acc[i][6] + bb[6], acc[i][7] + bb[7]);
        *(float4*)(r1 + (size_t)node * HID_F + ob) = o0;
        *(float4*)(r1 + (size_t)node * HID_F + ob + 4) = o1;
      }
    }
  } else {
#pragma unroll
    for (int i = 0; i < 8; ++i) {
      int node = n0 + ty * 8 + i;
      if (node < n_nodes) {
        __half hh[8];
#pragma unroll
        for (int j = 0; j < 8; ++j) hh[j] = __float2half(acc[i][j]);
        *(uint4*)(y1h + (size_t)node * HID_F + ob) = *(uint4*)hh;
      }
    }
  }
}

// ---------------------------------------------------------------------------
// agg1_fused: one wave per dst node. Quad-edge uint2 gathers:
// lane = (edge slot q 0..3, feature-quad f4 0..15). One gather instruction
// covers FOUR edges (16 lanes x 8B = 128B row each); 16 edges in flight per
// main-loop iteration. shfl_xor(16,32) merges edge slots.
// ---------------------------------------------------------------------------
__global__ __launch_bounds__(256) void agg1_fused(
    const __half* __restrict__ y1h,
    const float* __restrict__ r1,
    const int* __restrict__ deg_i,
    const int* __restrict__ offs,
    const int* __restrict__ csr_src,
    const float* __restrict__ mask,
    float* __restrict__ h,
    int n_nodes) {
  int node = (blockIdx.x * blockDim.x + threadIdx.x) >> 6;
  int lane = threadIdx.x & 63;
  if (node >= n_nodes) return;
  int q = lane >> 4;     // edge slot
  int f4 = lane & 15;    // features 4*f4 .. 4*f4+3
  int beg = offs[node];
  int d = deg_i[node];
  const int* cp = csr_src + beg;
  float a0 = 0.f, a1 = 0.f, a2 = 0.f, a3 = 0.f;
  int j = 0;
  for (; j + 16 <= d; j += 16) {
    int s0 = cp[j + q];
    int s1 = cp[j + 4 + q];
    int s2 = cp[j + 8 + q];
    int s3 = cp[j + 12 + q];
    uint2 g0 = *(const uint2*)(y1h + (size_t)s0 * HID_F + f4 * 4);
    uint2 g1 = *(const uint2*)(y1h + (size_t)s1 * HID_F + f4 * 4);
    uint2 g2 = *(const uint2*)(y1h + (size_t)s2 * HID_F + f4 * 4);
    uint2 g3 = *(const uint2*)(y1h + (size_t)s3 * HID_F + f4 * 4);
    float2 p0 = __half22float2(*(const __half2*)&g0.x);
    float2 p1 = __half22float2(*(const __half2*)&g0.y);
    float2 p2 = __half22float2(*(const __half2*)&g1.x);
    float2 p3 = __half22float2(*(const __half2*)&g1.y);
    float2 p4 = __half22float2(*(const __half2*)&g2.x);
    float2 p5 = __half22float2(*(const __half2*)&g2.y);
    float2 p6 = __half22float2(*(const __half2*)&g3.x);
    float2 p7 = __half22float2(*(const __half2*)&g3.y);
    a0 += (p0.x + p2.x) + (p4.x + p6.x);
    a1 += (p0.y + p2.y) + (p4.y + p6.y);
    a2 += (p1.x + p3.x) + (p5.x + p7.x);
    a3 += (p1.y + p3.y) + (p5.y + p7.y);
  }
  for (; j < d; j += 4) {
    int e = j + q;
    if (e < d) {
      int s = cp[e];
      uint2 g = *(const uint2*)(y1h + (size_t)s * HID_F + f4 * 4);
      float2 p0 = __half22float2(*(const __half2*)&g.x);
      float2 p1 = __half22float2(*(const __half2*)&g.y);
      a0 += p0.x; a1 += p0.y; a2 += p1.x; a3 += p1.y;
    }
  }
  // merge the 4 edge slots
  a0 += __shfl_xor(a0, 16); a0 += __shfl_xor(a0, 32);
  a1 += __shfl_xor(a1, 16); a1 += __shfl_xor(a1, 32);
  a2 += __shfl_xor(a2, 16); a2 += __shfl_xor(a2, 32);
  a3 += __shfl_xor(a3, 16); a3 += __shfl_xor(a3, 32);
  if (q == 0) {
    float inv = 1.0f / fmaxf((float)d, 1.0f);
    size_t o = (size_t)node * HID_F + f4 * 4;
    float4 rr = *(const float4*)(r1 + o);
    float4 mm = *(const float4*)(mask + o);
    float vx = fmaxf(a0 * inv + rr.x, 0.f);
    float vy = fmaxf(a1 * inv + rr.y, 0.f);
    float vz = fmaxf(a2 * inv + rr.z, 0.f);
    float vw = fmaxf(a3 * inv + rr.w, 0.f);
    vx = (mm.x > 0.5f) ? vx * 2.f : 0.f;
    vy = (mm.y > 0.5f) ? vy * 2.f : 0.f;
    vz = (mm.z > 0.5f) ? vz * 2.f : 0.f;
    vw = (mm.w > 0.5f) ? vw * 2.f : 0.f;
    *(float4*)(h + o) = make_float4(vx, vy, vz, vw);
  }
}

// ---------------------------------------------------------------------------
// k3b: z = h @ W2_l ([N,8], fp16 out -> z is 1.6 MB, L2-resident).
// ---------------------------------------------------------------------------
__global__ __launch_bounds__(256) void k3b_z(
    const float* __restrict__ h,
    const float* __restrict__ W2l,
    __half* __restrict__ z,
    int n_nodes) {
  __shared__ float WS[HID_F][OUT_F];
  int tid = threadIdx.x;
  if (tid < 128) {
    float4 w = *(const float4*)(W2l + tid * 4);
    *(float4*)&WS[tid >> 1][(tid & 1) * 4] = w;
  }
  __syncthreads();
  int node = blockIdx.x * blockDim.x + tid;
  if (node >= n_nodes) return;
  const float* hr = h + (size_t)node * HID_F;
  float acc[8] = {0, 0, 0, 0, 0, 0, 0, 0};
  for (int k = 0; k < HID_F; k += 4) {
    float4 hv = *(const float4*)(hr + k);
    float hh[4] = {hv.x, hv.y, hv.z, hv.w};
#pragma unroll
    for (int j = 0; j < 4; ++j) {
      float4 w0 = *(const float4*)&WS[k + j][0];
      float4 w1 = *(const float4*)&WS[k + j][4];
      acc[0] += hh[j] * w0.x; acc[1] += hh[j] * w0.y;
      acc[2] += hh[j] * w0.z; acc[3] += hh[j] * w0.w;
      acc[4] += hh[j] * w1.x; acc[5] += hh[j] * w1.y;
      acc[6] += hh[j] * w1.z; acc[7] += hh[j] * w1.w;
    }
  }
  __half hz[8];
#pragma unroll
  for (int j = 0; j < 8; ++j) hz[j] = __float2half(acc[j]);
  *(uint4*)(z + (size_t)node * OUT_F) = *(uint4*)hz;
}

// ---------------------------------------------------------------------------
// out_fused: one wave per batch element; layer-2 agg only at idx nodes.
// ---------------------------------------------------------------------------
__global__ __launch_bounds__(256) void out_fused(
    const int* __restrict__ idx,
    const __half* __restrict__ z,
    const int* __restrict__ deg_i,
    const int* __restrict__ offs,
    const int* __restrict__ csr_src,
    const float* __restrict__ h,
    const float* __restrict__ W2r,
    const float* __restrict__ b2,
    float* __restrict__ out,
    int n_batch) {
  int b = (blockIdx.x * blockDim.x + threadIdx.x) >> 6;
  int lane = threadIdx.x & 63;
  if (b >= n_batch) return;
  int i = idx[b];
  int e8 = lane >> 3;
  int o = lane & 7;
  int beg = offs[i];
  int d = deg_i[i];
  float acc = 0.f;
  for (int j = e8; j < d; j += 8) {
    int s = csr_src[beg + j];
    acc += __half2float(z[(size_t)s * OUT_F + o]);
  }
  float dv = fmaxf((float)d, 1.0f);
  float v = acc / dv;
  const float* hr = h + (size_t)i * HID_F;
#pragma unroll
  for (int jj = 0; jj < 8; ++jj) {
    int k = e8 * 8 + jj;
    v += hr[k] * W2r[k * OUT_F + o];
  }
  v += __shfl_xor(v, 8);
  v += __shfl_xor(v, 16);
  v += __shfl_xor(v, 32);
  if (e8 == 0) out[(size_t)b * OUT_F + o] = v + b2[o];
}

extern "C" void kernel_launch(void* const* d_in, const int* in_sizes, int n_in,
                              void* d_out, int out_size, void* d_ws, size_t ws_size,
                              hipStream_t stream) {
  const float* x    = (const float*)d_in[0];
  const int*   ei   = (const int*)d_in[1];
  const int*   idx  = (const int*)d_in[2];
  const float* mask = (const float*)d_in[3];
  const float* W1l  = (const float*)d_in[4];
  const float* W1r  = (const float*)d_in[5];
  const float* b1   = (const float*)d_in[6];
  const float* W2l  = (const float*)d_in[7];
  const float* W2r  = (const float*)d_in[8];
  const float* b2   = (const float*)d_in[9];
  float* out = (float*)d_out;

  int n_nodes = in_sizes[0] / IN_F;
  int n_edges = in_sizes[1] / 2;
  int n_batch = in_sizes[2];
  const int* src = ei;
  const int* dst = ei + n_edges;

  int nbuk = (n_nodes + BGRAN - 1) / BGRAN;   // 391
  int nchunk = (n_edges + CHUNK - 1) / CHUNK; // 391
  int nblk = (n_nodes + 1023) / 1024;         // 98

  // workspace; region A = union(y1h fp16 [N*64*2B], ebuf int2 [nbuk*BCAP*8B])
  char* ws = (char*)d_ws;
  size_t off = 0;
  size_t y1_bytes = (size_t)n_nodes * HID_F * sizeof(__half);
  size_t eb_bytes = (size_t)nbuk * BCAP * sizeof(int2);
  size_t regA = (y1_bytes > eb_bytes) ? y1_bytes : eb_bytes;
  __half* y1h = (__half*)(ws + off);
  int2* ebuf  = (int2*)(ws + off); off += regA;
  float* r1 = (float*)(ws + off); off += (size_t)n_nodes * HID_F * 4;
  float* h  = (float*)(ws + off); off += (size_t)n_nodes * HID_F * 4;
  __half* z = (__half*)(ws + off); off += (size_t)n_nodes * OUT_F * sizeof(__half);
  int* deg_i  = (int*)(ws + off); off += (size_t)n_nodes * 4;
  int* offs_l = (int*)(ws + off); off += (size_t)n_nodes * 4;
  int* offs_f = (int*)(ws + off); off += (size_t)n_nodes * 4;
  int* csr_src = (int*)(ws + off); off += (size_t)n_edges * 4;
  int* blk_sums = (int*)(ws + off); off += 256 * 4;
  int* bcur     = (int*)(ws + off); off += 512 * 4;

  // --- bucketed CSR build (no memsets, 6 dispatches) ---
  init_bcur<<<1, 512, 0, stream>>>(bcur);
  bucket_scatter<<<nchunk, 256, 0, stream>>>(src, dst, bcur, ebuf, n_edges);
  deg_kernel<<<nbuk, 256, 0, stream>>>(ebuf, bcur, deg_i, n_nodes);
  scan_local<<<nblk, 256, 0, stream>>>(deg_i, offs_l, blk_sums, n_nodes);
  scan_blk<<<1, 256, 0, stream>>>(blk_sums, nblk);
  csr_scatter<<<nbuk, 256, 0, stream>>>(ebuf, bcur, offs_l, blk_sums, offs_f, csr_src, n_nodes);

  // --- layer 1 ---
  k1_proj<<<(n_nodes + BM - 1) / BM, 256, 0, stream>>>(x, W1l, W1r, b1, y1h, r1, n_nodes);
  {
    long long th = (long long)n_nodes * HID_F;
    agg1_fused<<<(int)((th + 255) / 256), 256, 0, stream>>>(
        y1h, r1, deg_i, offs_f, csr_src, mask, h, n_nodes);
  }

  // --- layer 2 ---
  k3b_z<<<(n_nodes + 255) / 256, 256, 0, stream>>>(h, W2l, z, n_nodes);
  {
    long long th = (long long)n_batch * 64;
    out_fused<<<(int)((th + 255) / 256), 256, 0, stream>>>(idx, z, deg_i, offs_f, csr_src, h, W2r, b2, out, n_batch);
  }
}

// Round 9
// 267.245 us; speedup vs baseline: 8.2752x; 1.0441x over previous
//
#include <hip/hip_runtime.h>
#include <hip/hip_fp16.h>

#define IN_F 128
#define HID_F 64
#define OUT_F 8

// Bucketed CSR build: bucket = dst >> 7 (128 nodes/bucket).
// BCAP = 2688 >> mean 2046 + 14 sigma -> fixed-capacity runs, no global scan.
#define BSHIFT 7
#define BGRAN 128
#define BCAP 2688
#define NBUK_MAX 784
#define CHUNK 4096
#define EPT (CHUNK / 256)
#define CEPT ((BCAP + 255) / 256)   // 11

#if defined(__has_builtin)
#if __has_builtin(__builtin_amdgcn_fdot2)
#define HAS_FDOT2 1
#endif
#endif

typedef _Float16 h2v __attribute__((ext_vector_type(2)));

// ---------------------------------------------------------------------------
// init_bcur: bucket cursors at fixed-capacity bases.
// ---------------------------------------------------------------------------
__global__ __launch_bounds__(1024) void init_bcur(int* __restrict__ bcur, int nbuk) {
  int t = threadIdx.x;
  if (t < nbuk) bcur[t] = t * BCAP;
}

// ---------------------------------------------------------------------------
// bucket_scatter: per-chunk LDS histogram -> one global reserve per bucket ->
// write PACKED edges (dstLocal<<24 | src) grouped by bucket.
// ---------------------------------------------------------------------------
__global__ __launch_bounds__(256) void bucket_scatter(
    const int* __restrict__ src, const int* __restrict__ dst,
    int* __restrict__ bcur, int* __restrict__ ebuf, int n_edges) {
  __shared__ int hist[NBUK_MAX];
  __shared__ int base[NBUK_MAX];
  int t = threadIdx.x;
  for (int i = t; i < NBUK_MAX; i += 256) hist[i] = 0;
  __syncthreads();
  int e0 = blockIdx.x * CHUNK;
  int pk[EPT];
  int bk[EPT];
#pragma unroll
  for (int k = 0; k < EPT; ++k) {
    int e = e0 + k * 256 + t;
    if (e < n_edges) {
      int s = src[e];
      int d = dst[e];
      bk[k] = d >> BSHIFT;
      pk[k] = ((d & (BGRAN - 1)) << 24) | s;
      atomicAdd(&hist[bk[k]], 1);
    } else {
      bk[k] = -1;
    }
  }
  __syncthreads();
  for (int i = t; i < NBUK_MAX; i += 256) {
    int c = hist[i];
    base[i] = c ? atomicAdd(&bcur[i], c) : 0;
  }
  __syncthreads();
  for (int i = t; i < NBUK_MAX; i += 256) hist[i] = 0;
  __syncthreads();
#pragma unroll
  for (int k = 0; k < EPT; ++k) {
    if (bk[k] >= 0) {
      int r = atomicAdd(&hist[bk[k]], 1);
      ebuf[base[bk[k]] + r] = pk[k];
    }
  }
}

// ---------------------------------------------------------------------------
// bucket_csr: ONE kernel per bucket replaces deg+scan_local+scan_blk+
// csr_scatter. Counting-sort of the bucket's edges entirely in LDS:
// hist -> local exclusive scan -> place -> coalesced stream-out.
// offs_f[node] = bucket_base + local_prefix (global scan unnecessary since
// csr_src keeps per-bucket fixed-capacity runs).
// ---------------------------------------------------------------------------
__global__ __launch_bounds__(256) void bucket_csr(
    const int* __restrict__ ebuf, const int* __restrict__ bcur,
    int* __restrict__ offs_f, int* __restrict__ deg_i,
    int* __restrict__ csr_src, int n_nodes) {
  __shared__ int hist[BGRAN];
  __shared__ int cur[BGRAN];
  __shared__ int s[BGRAN];
  __shared__ int lds_src[BCAP];
  int b = blockIdx.x;
  int t = threadIdx.x;
  if (t < BGRAN) hist[t] = 0;
  __syncthreads();
  int beg = b * BCAP;
  int cnt = bcur[b] - beg;
  int pk[CEPT];
  int np = 0;
  for (int j = t; j < cnt; j += 256) {
    pk[np] = ebuf[beg + j];
    atomicAdd(&hist[(unsigned)pk[np] >> 24], 1);
    ++np;
  }
  __syncthreads();
  if (t < BGRAN) s[t] = hist[t];
  __syncthreads();
  for (int d = 1; d < BGRAN; d <<= 1) {
    int v = 0;
    if (t >= d && t < BGRAN) v = s[t - d];
    __syncthreads();
    if (t >= d && t < BGRAN) s[t] += v;
    __syncthreads();
  }
  if (t < BGRAN) {
    int excl = (t == 0) ? 0 : s[t - 1];
    cur[t] = excl;
    int node = b * BGRAN + t;
    if (node < n_nodes) {
      offs_f[node] = beg + excl;
      deg_i[node] = hist[t];
    }
  }
  __syncthreads();
  for (int i = 0; i < np; ++i) {
    int dl = (unsigned)pk[i] >> 24;
    int p = atomicAdd(&cur[dl], 1);
    lds_src[p] = pk[i] & 0xFFFFFF;
  }
  __syncthreads();
  for (int j = t; j < cnt; j += 256) csr_src[beg + j] = lds_src[j];
}

// ---------------------------------------------------------------------------
// k1: LDS-tiled GEMM with packed-f16 dot2 inner loop.
// y1 fp16, r1 fp16. Also packs dropout mask -> 1 bit/feature (uint64/node).
// ---------------------------------------------------------------------------
#define BM 128
#define BK 32
__global__ __launch_bounds__(256, 4) void k1_proj(
    const float* __restrict__ x,
    const float* __restrict__ Wl,
    const float* __restrict__ Wr,
    const float* __restrict__ b1,
    const float* __restrict__ mask,
    __half* __restrict__ y1h,
    __half* __restrict__ r1h,
    unsigned long long* __restrict__ mbits,
    int n_nodes) {
  __shared__ h2v XS2[BK / 2][BM];
  __shared__ h2v WS2[BK / 2][128];
  int tid = threadIdx.x;
  int tx = tid & 15;
  int ty = tid >> 4;
  int n0 = blockIdx.x * BM;

  // mask bit-pack: wave w handles nodes n0 + {w, w+4, ...}; lane = feature.
  {
    int w = tid >> 6;
    int lane = tid & 63;
    for (int i = w; i < BM; i += 4) {
      int node = n0 + i;
      if (node < n_nodes) {
        float mv = mask[(size_t)node * HID_F + lane];
        unsigned long long bits = __ballot(mv > 0.5f);
        if (lane == 0) mbits[node] = bits;
      }
    }
  }

  float acc[8][8];
#pragma unroll
  for (int i = 0; i < 8; ++i)
#pragma unroll
    for (int j = 0; j < 8; ++j) acc[i][j] = 0.f;

  for (int kb = 0; kb < IN_F; kb += BK) {
    {
      int nn0 = tid >> 3;
      int k4 = (tid & 7) * 4;
      int kp0 = (tid & 7) * 2;
#pragma unroll
      for (int p = 0; p < 4; ++p) {
        int nn = nn0 + p * 32;
        int gs = min(n0 + nn, n_nodes - 1);
        float4 v = *(const float4*)(x + (size_t)gs * IN_F + kb + k4);
        XS2[kp0][nn] = h2v{(_Float16)v.x, (_Float16)v.y};
        XS2[kp0 + 1][nn] = h2v{(_Float16)v.z, (_Float16)v.w};
      }
    }
    {
#pragma unroll
      for (int p = 0; p < 2; ++p) {
        int sidx = tid + p * 256;
        int kp = sidx >> 5;
        int col = (sidx & 31) * 4;
        int k0 = kb + kp * 2;
        const float* pa = (col < 64) ? (Wl + (size_t)k0 * HID_F + col)
                                     : (Wr + (size_t)k0 * HID_F + (col - 64));
        const float* pb = (col < 64) ? (Wl + (size_t)(k0 + 1) * HID_F + col)
                                     : (Wr + (size_t)(k0 + 1) * HID_F + (col - 64));
        float4 wa = *(const float4*)pa;
        float4 wb = *(const float4*)pb;
        WS2[kp][col + 0] = h2v{(_Float16)wa.x, (_Float16)wb.x};
        WS2[kp][col + 1] = h2v{(_Float16)wa.y, (_Float16)wb.y};
        WS2[kp][col + 2] = h2v{(_Float16)wa.z, (_Float16)wb.z};
        WS2[kp][col + 3] = h2v{(_Float16)wa.w, (_Float16)wb.w};
      }
    }
    __syncthreads();
#pragma unroll 4
    for (int kp = 0; kp < BK / 2; ++kp) {
      h2v xv[8], wv[8];
#pragma unroll
      for (int i = 0; i < 8; ++i) xv[i] = XS2[kp][ty * 8 + i];
#pragma unroll
      for (int j = 0; j < 8; ++j) wv[j] = WS2[kp][tx * 8 + j];
#pragma unroll
      for (int i = 0; i < 8; ++i)
#pragma unroll
        for (int j = 0; j < 8; ++j) {
#ifdef HAS_FDOT2
          acc[i][j] = __builtin_amdgcn_fdot2(xv[i], wv[j], acc[i][j], false);
#else
          acc[i][j] += (float)xv[i][0] * (float)wv[j][0] +
                       (float)xv[i][1] * (float)wv[j][1];
#endif
        }
    }
    __syncthreads();
  }

  int outb = tx * 8;
  bool isR = (outb >= HID_F);
  int ob = isR ? outb - HID_F : outb;
  __half* dbuf = isR ? r1h : y1h;
  float bb[8];
#pragma unroll
  for (int j = 0; j < 8; ++j) bb[j] = isR ? b1[ob + j] : 0.f;
#pragma unroll
  for (int i = 0; i < 8; ++i) {
    int node = n0 + ty * 8 + i;
    if (node < n_nodes) {
      __half hh[8];
#pragma unroll
      for (int j = 0; j < 8; ++j) hh[j] = __float2half(acc[i][j] + bb[j]);
      *(uint4*)(dbuf + (size_t)node * HID_F + ob) = *(uint4*)hh;
    }
  }
}

// ---------------------------------------------------------------------------
// agg1_fused: one wave per dst node; quad-edge uint2 gathers (16 edges in
// flight). fp16 r1, bitmask dropout, fp16 h output.
// ---------------------------------------------------------------------------
__global__ __launch_bounds__(256) void agg1_fused(
    const __half* __restrict__ y1h,
    const __half* __restrict__ r1h,
    const int* __restrict__ deg_i,
    const int* __restrict__ offs,
    const int* __restrict__ csr_src,
    const unsigned long long* __restrict__ mbits,
    __half* __restrict__ h_h,
    int n_nodes) {
  int node = (blockIdx.x * blockDim.x + threadIdx.x) >> 6;
  int lane = threadIdx.x & 63;
  if (node >= n_nodes) return;
  int q = lane >> 4;
  int f4 = lane & 15;
  int beg = offs[node];
  int d = deg_i[node];
  const int* cp = csr_src + beg;
  float a0 = 0.f, a1 = 0.f, a2 = 0.f, a3 = 0.f;
  int j = 0;
  for (; j + 16 <= d; j += 16) {
    int s0 = cp[j + q];
    int s1 = cp[j + 4 + q];
    int s2 = cp[j + 8 + q];
    int s3 = cp[j + 12 + q];
    uint2 g0 = *(const uint2*)(y1h + (size_t)s0 * HID_F + f4 * 4);
    uint2 g1 = *(const uint2*)(y1h + (size_t)s1 * HID_F + f4 * 4);
    uint2 g2 = *(const uint2*)(y1h + (size_t)s2 * HID_F + f4 * 4);
    uint2 g3 = *(const uint2*)(y1h + (size_t)s3 * HID_F + f4 * 4);
    float2 p0 = __half22float2(*(const __half2*)&g0.x);
    float2 p1 = __half22float2(*(const __half2*)&g0.y);
    float2 p2 = __half22float2(*(const __half2*)&g1.x);
    float2 p3 = __half22float2(*(const __half2*)&g1.y);
    float2 p4 = __half22float2(*(const __half2*)&g2.x);
    float2 p5 = __half22float2(*(const __half2*)&g2.y);
    float2 p6 = __half22float2(*(const __half2*)&g3.x);
    float2 p7 = __half22float2(*(const __half2*)&g3.y);
    a0 += (p0.x + p2.x) + (p4.x + p6.x);
    a1 += (p0.y + p2.y) + (p4.y + p6.y);
    a2 += (p1.x + p3.x) + (p5.x + p7.x);
    a3 += (p1.y + p3.y) + (p5.y + p7.y);
  }
  for (; j < d; j += 4) {
    int e = j + q;
    if (e < d) {
      int s = cp[e];
      uint2 g = *(const uint2*)(y1h + (size_t)s * HID_F + f4 * 4);
      float2 p0 = __half22float2(*(const __half2*)&g.x);
      float2 p1 = __half22float2(*(const __half2*)&g.y);
      a0 += p0.x; a1 += p0.y; a2 += p1.x; a3 += p1.y;
    }
  }
  a0 += __shfl_xor(a0, 16); a0 += __shfl_xor(a0, 32);
  a1 += __shfl_xor(a1, 16); a1 += __shfl_xor(a1, 32);
  a2 += __shfl_xor(a2, 16); a2 += __shfl_xor(a2, 32);
  a3 += __shfl_xor(a3, 16); a3 += __shfl_xor(a3, 32);
  if (q == 0) {
    float inv = 1.0f / fmaxf((float)d, 1.0f);
    size_t o = (size_t)node * HID_F + f4 * 4;
    uint2 rg = *(const uint2*)(r1h + o);
    float2 r01 = __half22float2(*(const __half2*)&rg.x);
    float2 r23 = __half22float2(*(const __half2*)&rg.y);
    unsigned long long mb = mbits[node];
    float vx = fmaxf(a0 * inv + r01.x, 0.f);
    float vy = fmaxf(a1 * inv + r01.y, 0.f);
    float vz = fmaxf(a2 * inv + r23.x, 0.f);
    float vw = fmaxf(a3 * inv + r23.y, 0.f);
    int fb = f4 * 4;
    vx = ((mb >> (fb + 0)) & 1ull) ? vx * 2.f : 0.f;
    vy = ((mb >> (fb + 1)) & 1ull) ? vy * 2.f : 0.f;
    vz = ((mb >> (fb + 2)) & 1ull) ? vz * 2.f : 0.f;
    vw = ((mb >> (fb + 3)) & 1ull) ? vw * 2.f : 0.f;
    __half hh[4] = {__float2half(vx), __float2half(vy),
                    __float2half(vz), __float2half(vw)};
    *(uint2*)(h_h + o) = *(uint2*)hh;
  }
}

// ---------------------------------------------------------------------------
// k3b: z = h @ W2_l ([N,8] fp16). h fp16 in, W2_l in LDS.
// ---------------------------------------------------------------------------
__global__ __launch_bounds__(256) void k3b_z(
    const __half* __restrict__ h_h,
    const float* __restrict__ W2l,
    __half* __restrict__ z,
    int n_nodes) {
  __shared__ float WS[HID_F][OUT_F];
  int tid = threadIdx.x;
  if (tid < 128) {
    float4 w = *(const float4*)(W2l + tid * 4);
    *(float4*)&WS[tid >> 1][(tid & 1) * 4] = w;
  }
  __syncthreads();
  int node = blockIdx.x * blockDim.x + tid;
  if (node >= n_nodes) return;
  const __half* hr = h_h + (size_t)node * HID_F;
  float acc[8] = {0, 0, 0, 0, 0, 0, 0, 0};
  for (int k = 0; k < HID_F; k += 8) {
    uint4 hv = *(const uint4*)(hr + k);
    float2 f0 = __half22float2(*(const __half2*)&hv.x);
    float2 f1 = __half22float2(*(const __half2*)&hv.y);
    float2 f2 = __half22float2(*(const __half2*)&hv.z);
    float2 f3 = __half22float2(*(const __half2*)&hv.w);
    float hh[8] = {f0.x, f0.y, f1.x, f1.y, f2.x, f2.y, f3.x, f3.y};
#pragma unroll
    for (int j = 0; j < 8; ++j) {
      float4 w0 = *(const float4*)&WS[k + j][0];
      float4 w1 = *(const float4*)&WS[k + j][4];
      acc[0] += hh[j] * w0.x; acc[1] += hh[j] * w0.y;
      acc[2] += hh[j] * w0.z; acc[3] += hh[j] * w0.w;
      acc[4] += hh[j] * w1.x; acc[5] += hh[j] * w1.y;
      acc[6] += hh[j] * w1.z; acc[7] += hh[j] * w1.w;
    }
  }
  __half hz[8];
#pragma unroll
  for (int j = 0; j < 8; ++j) hz[j] = __float2half(acc[j]);
  *(uint4*)(z + (size_t)node * OUT_F) = *(uint4*)hz;
}

// ---------------------------------------------------------------------------
// out_fused: one wave per batch element; layer-2 agg only at idx nodes.
// ---------------------------------------------------------------------------
__global__ __launch_bounds__(256) void out_fused(
    const int* __restrict__ idx,
    const __half* __restrict__ z,
    const int* __restrict__ deg_i,
    const int* __restrict__ offs,
    const int* __restrict__ csr_src,
    const __half* __restrict__ h_h,
    const float* __restrict__ W2r,
    const float* __restrict__ b2,
    float* __restrict__ out,
    int n_batch) {
  int b = (blockIdx.x * blockDim.x + threadIdx.x) >> 6;
  int lane = threadIdx.x & 63;
  if (b >= n_batch) return;
  int i = idx[b];
  int e8 = lane >> 3;
  int o = lane & 7;
  int beg = offs[i];
  int d = deg_i[i];
  float acc = 0.f;
  for (int j = e8; j < d; j += 8) {
    int s = csr_src[beg + j];
    acc += __half2float(z[(size_t)s * OUT_F + o]);
  }
  float dv = fmaxf((float)d, 1.0f);
  float v = acc / dv;
  // root term: 8 contiguous k per subgroup; h row fp16 (16B per lane)
  uint4 hv = *(const uint4*)(h_h + (size_t)i * HID_F + e8 * 8);
  float2 f0 = __half22float2(*(const __half2*)&hv.x);
  float2 f1 = __half22float2(*(const __half2*)&hv.y);
  float2 f2 = __half22float2(*(const __half2*)&hv.z);
  float2 f3 = __half22float2(*(const __half2*)&hv.w);
  float hh[8] = {f0.x, f0.y, f1.x, f1.y, f2.x, f2.y, f3.x, f3.y};
#pragma unroll
  for (int jj = 0; jj < 8; ++jj) {
    int k = e8 * 8 + jj;
    v += hh[jj] * W2r[k * OUT_F + o];
  }
  v += __shfl_xor(v, 8);
  v += __shfl_xor(v, 16);
  v += __shfl_xor(v, 32);
  if (e8 == 0) out[(size_t)b * OUT_F + o] = v + b2[o];
}

extern "C" void kernel_launch(void* const* d_in, const int* in_sizes, int n_in,
                              void* d_out, int out_size, void* d_ws, size_t ws_size,
                              hipStream_t stream) {
  const float* x    = (const float*)d_in[0];
  const int*   ei   = (const int*)d_in[1];
  const int*   idx  = (const int*)d_in[2];
  const float* mask = (const float*)d_in[3];
  const float* W1l  = (const float*)d_in[4];
  const float* W1r  = (const float*)d_in[5];
  const float* b1   = (const float*)d_in[6];
  const float* W2l  = (const float*)d_in[7];
  const float* W2r  = (const float*)d_in[8];
  const float* b2   = (const float*)d_in[9];
  float* out = (float*)d_out;

  int n_nodes = in_sizes[0] / IN_F;
  int n_edges = in_sizes[1] / 2;
  int n_batch = in_sizes[2];
  const int* src = ei;
  const int* dst = ei + n_edges;

  int nbuk = (n_nodes + BGRAN - 1) / BGRAN;   // 782
  int nchunk = (n_edges + CHUNK - 1) / CHUNK; // 391

  // workspace
  char* ws = (char*)d_ws;
  size_t off = 0;
  __half* y1h = (__half*)(ws + off); off += (size_t)n_nodes * HID_F * 2;
  __half* r1h = (__half*)(ws + off); off += (size_t)n_nodes * HID_F * 2;
  __half* h_h = (__half*)(ws + off); off += (size_t)n_nodes * HID_F * 2;
  __half* z   = (__half*)(ws + off); off += (size_t)n_nodes * OUT_F * 2;
  unsigned long long* mbits = (unsigned long long*)(ws + off); off += (size_t)n_nodes * 8;
  int* ebuf    = (int*)(ws + off); off += (size_t)nbuk * BCAP * 4;
  int* csr_src = (int*)(ws + off); off += (size_t)nbuk * BCAP * 4;
  int* deg_i   = (int*)(ws + off); off += (size_t)n_nodes * 4;
  int* offs_f  = (int*)(ws + off); off += (size_t)n_nodes * 4;
  int* bcur    = (int*)(ws + off); off += NBUK_MAX * 4;

  // --- CSR build: 3 dispatches ---
  init_bcur<<<1, 1024, 0, stream>>>(bcur, nbuk);
  bucket_scatter<<<nchunk, 256, 0, stream>>>(src, dst, bcur, ebuf, n_edges);
  // k1 is independent of the build; launch between build stages for overlap slack
  k1_proj<<<(n_nodes + BM - 1) / BM, 256, 0, stream>>>(
      x, W1l, W1r, b1, mask, y1h, r1h, mbits, n_nodes);
  bucket_csr<<<nbuk, 256, 0, stream>>>(ebuf, bcur, offs_f, deg_i, csr_src, n_nodes);

  // --- layer 1 aggregation ---
  {
    long long th = (long long)n_nodes * HID_F;
    agg1_fused<<<(int)((th + 255) / 256), 256, 0, stream>>>(
        y1h, r1h, deg_i, offs_f, csr_src, mbits, h_h, n_nodes);
  }

  // --- layer 2 ---
  k3b_z<<<(n_nodes + 255) / 256, 256, 0, stream>>>(h_h, W2l, z, n_nodes);
  {
    long long th = (long long)n_batch * 64;
    out_fused<<<(int)((th + 255) / 256), 256, 0, stream>>>(
        idx, z, deg_i, offs_f, csr_src, h_h, W2r, b2, out, n_batch);
  }
}